// Round 10
// baseline (661.961 us; speedup 1.0000x reference)
//
#include <hip/hip_runtime.h>
#include <hip/hip_bf16.h>
#include <math.h>

#define D 2048
#define M_ROWS 50000
#define B_ROWS 16384
#define TOPK 5
#define EPSN 1e-12f

typedef __attribute__((ext_vector_type(4))) float f32x4;
typedef __attribute__((ext_vector_type(8))) short s16x8;
typedef __attribute__((ext_vector_type(4))) unsigned short u16x4;

__device__ __forceinline__ unsigned short f2bf(float f) {
  union { float f; unsigned int u; } x; x.f = f;
  unsigned int u = x.u;
  unsigned int r = u + 0x7fffu + ((u >> 16) & 1u);
  return (unsigned short)(r >> 16);
}

__device__ __forceinline__ void gload16(const void* g, void* l) {
  __builtin_amdgcn_global_load_lds(
      (const __attribute__((address_space(1))) unsigned int*)g,
      (__attribute__((address_space(3))) unsigned int*)l, 16, 0, 0);
}

// Subtiled bf16 layout for A_sw/B_sw, per 16-row x 64-K block (2048 elems):
//   addr(row,k) = ((row>>4)*32 + (k>>6))*1024 + ((k>>5)&1)*512 + ((k>>3)&3)*128 + (row&15)*8 + (k&7)
// => segment address for (rowhi, K-half h) is LINEAR: rowhi*32768 + h*512 elems.
// Wave-contiguous: lane L <-> (rlow=L&15, kq=L>>4); one 1KB segment per wave op.

// ---------------- K1: sims over memory bank (qnorm fused per-block) ----------------
__global__ void k_sims(const float* __restrict__ bank, const float* __restrict__ ce,
                       float* __restrict__ sims) {
  __shared__ float qs[D];
  __shared__ float red[256];
  int tid = threadIdx.x;
  float s = 0.f;
  for (int t = tid; t < D; t += 256) { float x = ce[t]; s += x * x; }
  red[tid] = s; __syncthreads();
  for (int w = 128; w > 0; w >>= 1) { if (tid < w) red[tid] += red[tid + w]; __syncthreads(); }
  float qinv = 1.0f / fmaxf(sqrtf(red[0]), EPSN);
  for (int t = tid; t < D; t += 256) qs[t] = ce[t] * qinv;
  __syncthreads();
  int lane = tid & 63, wid = tid >> 6;
  int gw = (blockIdx.x << 2) + wid;
  int nw = gridDim.x << 2;
  for (int m = gw; m < M_ROWS; m += nw) {
    const float* row = bank + (size_t)m * D;
    float dot = 0.f, sq = 0.f;
#pragma unroll
    for (int i = 0; i < 8; ++i) {
      int off = i * 256 + lane * 4;
      f32x4 a = *(const f32x4*)(row + off);
      f32x4 q = *(const f32x4*)(qs + off);
      dot += a[0]*q[0] + a[1]*q[1] + a[2]*q[2] + a[3]*q[3];
      sq  += a[0]*a[0] + a[1]*a[1] + a[2]*a[2] + a[3]*a[3];
    }
    for (int off = 32; off; off >>= 1) {
      dot += __shfl_xor(dot, off, 64);
      sq  += __shfl_xor(sq,  off, 64);
    }
    if (lane == 0) sims[m] = dot / fmaxf(sqrtf(sq), EPSN);
  }
}

// ---------------- K2: top-5 ----------------
__global__ void k_topk(const float* __restrict__ sims, float* __restrict__ top_sims,
                       int* __restrict__ top_idx) {
  __shared__ float sval[256 * TOPK];
  __shared__ int   sidx[256 * TOPK];
  __shared__ float sv2[64 * TOPK];
  __shared__ int   si2[64 * TOPK];
  int tid = threadIdx.x;
  float lv[TOPK]; int li[TOPK];
#pragma unroll
  for (int j = 0; j < TOPK; ++j) { lv[j] = -INFINITY; li[j] = 0x7fffffff; }
  for (int m = tid; m < M_ROWS; m += 256) {
    float v = sims[m];
    if (v > lv[TOPK-1] || (v == lv[TOPK-1] && m < li[TOPK-1])) {
      lv[TOPK-1] = v; li[TOPK-1] = m;
#pragma unroll
      for (int j = TOPK-1; j > 0; --j) {
        bool sw = (lv[j] > lv[j-1]) || (lv[j] == lv[j-1] && li[j] < li[j-1]);
        if (sw) { float tv=lv[j]; lv[j]=lv[j-1]; lv[j-1]=tv; int ti=li[j]; li[j]=li[j-1]; li[j-1]=ti; }
      }
    }
  }
#pragma unroll
  for (int j = 0; j < TOPK; ++j) { sval[tid*TOPK+j] = lv[j]; sidx[tid*TOPK+j] = li[j]; }
  __syncthreads();
  if (tid < 64) {
    float bv[TOPK]; int bi[TOPK];
    for (int j = 0; j < TOPK; ++j) { bv[j] = -INFINITY; bi[j] = 0x7fffffff; }
    for (int c = tid * 20; c < tid * 20 + 20; ++c) {
      float v = sval[c]; int i = sidx[c];
      if (v > bv[TOPK-1] || (v == bv[TOPK-1] && i < bi[TOPK-1])) {
        bv[TOPK-1] = v; bi[TOPK-1] = i;
        for (int j = TOPK-1; j > 0; --j) {
          bool sw = (bv[j] > bv[j-1]) || (bv[j] == bv[j-1] && bi[j] < bi[j-1]);
          if (sw) { float tv=bv[j]; bv[j]=bv[j-1]; bv[j-1]=tv; int ti=bi[j]; bi[j]=bi[j-1]; bi[j-1]=ti; }
        }
      }
    }
    for (int j = 0; j < TOPK; ++j) { sv2[tid*TOPK+j] = bv[j]; si2[tid*TOPK+j] = bi[j]; }
  }
  __syncthreads();
  if (tid == 0) {
    float bvv[TOPK]; int bii[TOPK];
    for (int j = 0; j < TOPK; ++j) { bvv[j] = -INFINITY; bii[j] = 0x7fffffff; }
    for (int c = 0; c < 64 * TOPK; ++c) {
      float v = sv2[c]; int i = si2[c];
      if (v > bvv[TOPK-1] || (v == bvv[TOPK-1] && i < bii[TOPK-1])) {
        bvv[TOPK-1] = v; bii[TOPK-1] = i;
        for (int j = TOPK-1; j > 0; --j) {
          bool sw = (bvv[j] > bvv[j-1]) || (bvv[j] == bvv[j-1] && bii[j] < bii[j-1]);
          if (sw) { float tv=bvv[j]; bvv[j]=bvv[j-1]; bvv[j-1]=tv; int ti=bii[j]; bii[j]=bii[j-1]; bii[j-1]=ti; }
        }
      }
    }
    for (int j = 0; j < TOPK; ++j) { top_sims[j] = bvv[j]; top_idx[j] = bii[j]; }
  }
}

// ---------------- K3: k,v = memories @ Wk/Wv^T + b ----------------
__global__ void k_kv(const float* __restrict__ mvals, const int* __restrict__ top_idx,
                     const float* __restrict__ Wk, const float* __restrict__ bk,
                     const float* __restrict__ Wv, const float* __restrict__ bvp,
                     float* __restrict__ kb, float* __restrict__ vb) {
  __shared__ float mem[TOPK][D];
  int tid = threadIdx.x;
  for (int j = 0; j < TOPK; ++j) {
    const float* src = mvals + (size_t)top_idx[j] * D;
    for (int t = tid; t < D; t += 256) mem[j][t] = src[t];
  }
  __syncthreads();
  int lane = tid & 63, wid = tid >> 6;
  int c = blockIdx.x * 4 + wid;
  const float* wkr = Wk + (size_t)c * D;
  const float* wvr = Wv + (size_t)c * D;
  float ak[TOPK] = {0,0,0,0,0}, av[TOPK] = {0,0,0,0,0};
#pragma unroll 2
  for (int i = 0; i < 8; ++i) {
    int off = i * 256 + lane * 4;
    f32x4 wk4 = *(const f32x4*)(wkr + off);
    f32x4 wv4 = *(const f32x4*)(wvr + off);
#pragma unroll
    for (int j = 0; j < TOPK; ++j) {
      f32x4 mv = *(const f32x4*)(&mem[j][off]);
      ak[j] += mv[0]*wk4[0] + mv[1]*wk4[1] + mv[2]*wk4[2] + mv[3]*wk4[3];
      av[j] += mv[0]*wv4[0] + mv[1]*wv4[1] + mv[2]*wv4[2] + mv[3]*wv4[3];
    }
  }
  for (int off = 32; off; off >>= 1) {
#pragma unroll
    for (int j = 0; j < TOPK; ++j) {
      ak[j] += __shfl_xor(ak[j], off, 64);
      av[j] += __shfl_xor(av[j], off, 64);
    }
  }
  if (lane == 0) {
#pragma unroll
    for (int j = 0; j < TOPK; ++j) { kb[j*D + c] = ak[j] + bk[c]; vb[j*D + c] = av[j] + bvp[c]; }
  }
}

// ---------------- K4: prep — KQ partials, VW, sbias, WgA bf16 cast (wave-coalesced) ----
__global__ void k_prep(const float* __restrict__ Wq, const float* __restrict__ bq,
                       const float* __restrict__ Wg,
                       const float* __restrict__ kb, const float* __restrict__ vb,
                       float* __restrict__ KQpart, float* __restrict__ VW,
                       float* __restrict__ sbias, unsigned short* __restrict__ B_sw) {
  __shared__ float sh[TOPK * D];
  int tid = threadIdx.x;
  int bid = blockIdx.x;
  if (bid < 256) {
    int cc = bid >> 3, tc = bid & 7;
    for (int x = tid; x < TOPK * 64; x += 256) sh[x] = kb[(x >> 6) * D + cc * 64 + (x & 63)];
    __syncthreads();
    float acc[TOPK] = {0,0,0,0,0};
    const float* wq = Wq + (size_t)(cc * 64) * D + tc * 256 + tid;
#pragma unroll 4
    for (int c = 0; c < 64; ++c) {
      float w = wq[(size_t)c * D];
#pragma unroll
      for (int j = 0; j < TOPK; ++j) acc[j] += sh[j * 64 + c] * w;
    }
#pragma unroll
    for (int j = 0; j < TOPK; ++j)
      KQpart[(size_t)(cc * TOPK + j) * D + tc * 256 + tid] = acc[j];
  } else if (bid < 768) {
    for (int x = tid; x < TOPK * D; x += 256) sh[x] = vb[x];
    __syncthreads();
    int lane = tid & 63, wid = tid >> 6;
    int c = (bid - 256) * 4 + wid;
    const float* wg = Wg + (size_t)c * (2 * D) + D;
    float acc[TOPK] = {0,0,0,0,0};
#pragma unroll 2
    for (int i = 0; i < 8; ++i) {
      int off = i * 256 + lane * 4;
      f32x4 g4 = *(const f32x4*)(wg + off);
#pragma unroll
      for (int j = 0; j < TOPK; ++j) {
        f32x4 vv = *(const f32x4*)(&sh[j*D + off]);
        acc[j] += vv[0]*g4[0] + vv[1]*g4[1] + vv[2]*g4[2] + vv[3]*g4[3];
      }
    }
    for (int off = 32; off; off >>= 1)
#pragma unroll
      for (int j = 0; j < TOPK; ++j) acc[j] += __shfl_xor(acc[j], off, 64);
    if (lane == 0)
      for (int j = 0; j < TOPK; ++j) VW[j*D + c] = acc[j];
  } else if (bid == 768) {
    for (int j = 0; j < TOPK; ++j) {
      float s = 0.f;
      for (int t = tid; t < D; t += 256) s += bq[t] * kb[j*D + t];
      sh[tid] = s; __syncthreads();
      for (int w = 128; w > 0; w >>= 1) { if (tid < w) sh[tid] += sh[tid + w]; __syncthreads(); }
      if (tid == 0) sbias[j] = sh[0];
      __syncthreads();
    }
  } else {
    int lane = tid & 63, wid = tid >> 6;
    int r0 = ((bid - 769) * 4 + wid) * 16;
    int rl = lane & 15, kg = lane >> 4;
    const float* src = Wg + (size_t)(r0 + rl) * (2 * D);
    size_t wbase = ((size_t)(r0 >> 4) * 32) << 10;
#pragma unroll 4
    for (int it = 0; it < 64; ++it) {
      int k = it * 32 + kg * 8;
      f32x4 a = *(const f32x4*)(src + k);
      f32x4 b = *(const f32x4*)(src + k + 4);
      s16x8 p;
      p[0]=(short)f2bf(a[0]); p[1]=(short)f2bf(a[1]); p[2]=(short)f2bf(a[2]); p[3]=(short)f2bf(a[3]);
      p[4]=(short)f2bf(b[0]); p[5]=(short)f2bf(b[1]); p[6]=(short)f2bf(b[2]); p[7]=(short)f2bf(b[3]);
      *(s16x8*)(B_sw + wbase + ((size_t)it << 9) + lane * 8) = p;
    }
  }
}

// ---------------- K4b: reduce 32 KQ partials -> KQ ----------------
__global__ void k_red(const float* __restrict__ KQpart, float* __restrict__ KQ) {
  int x = blockIdx.x * 256 + threadIdx.x;
  float s = 0.f;
#pragma unroll 8
  for (int cc = 0; cc < 32; ++cc) s += KQpart[(size_t)cc * (TOPK * D) + x];
  KQ[x] = s;
}

// ---------------- K5: scores + softmax + fused no->bf16 subtiled coalesced cast ------
template <bool WRITE_CAST>
__global__ void k_attn(const float* __restrict__ no, const float* __restrict__ KQ,
                       const float* __restrict__ sbias, const float* __restrict__ top_sims,
                       float* __restrict__ attn, unsigned short* __restrict__ A_sw) {
  __shared__ float kq[TOPK * D];
  int tid = threadIdx.x;
  for (int x = tid; x < TOPK * D; x += 256) kq[x] = KQ[x];
  __syncthreads();
  int lane = tid & 63, wid = tid >> 6;
  int b0 = (blockIdx.x * 4 + wid) * 16;
  int rl = lane & 15, kg = lane >> 4;
  const float* row = no + (size_t)(b0 + rl) * D;
  size_t wbase = ((size_t)(b0 >> 4) * 32) << 10;
  float acc[TOPK] = {0, 0, 0, 0, 0};
#pragma unroll 4
  for (int it = 0; it < 64; ++it) {
    int k = it * 32 + kg * 8;
    f32x4 a = __builtin_nontemporal_load((const f32x4*)(row + k));
    f32x4 b = __builtin_nontemporal_load((const f32x4*)(row + k + 4));
#pragma unroll
    for (int j = 0; j < TOPK; ++j) {
      f32x4 ka = *(const f32x4*)(&kq[j * D + k]);
      f32x4 kb2 = *(const f32x4*)(&kq[j * D + k + 4]);
      acc[j] += a[0]*ka[0] + a[1]*ka[1] + a[2]*ka[2] + a[3]*ka[3]
              + b[0]*kb2[0] + b[1]*kb2[1] + b[2]*kb2[2] + b[3]*kb2[3];
    }
    if (WRITE_CAST) {
      s16x8 p;
      p[0]=(short)f2bf(a[0]); p[1]=(short)f2bf(a[1]); p[2]=(short)f2bf(a[2]); p[3]=(short)f2bf(a[3]);
      p[4]=(short)f2bf(b[0]); p[5]=(short)f2bf(b[1]); p[6]=(short)f2bf(b[2]); p[7]=(short)f2bf(b[3]);
      *(s16x8*)(A_sw + wbase + ((size_t)it << 9) + lane * 8) = p;
    }
  }
#pragma unroll
  for (int j = 0; j < TOPK; ++j) {
    acc[j] += __shfl_xor(acc[j], 16, 64);
    acc[j] += __shfl_xor(acc[j], 32, 64);
  }
  if (lane < 16) {
    const float inv = 0.02209708691207961f;  // 1/sqrt(2048)
    float s[TOPK], mx = -INFINITY;
#pragma unroll
    for (int j = 0; j < TOPK; ++j) { s[j] = (acc[j] + sbias[j]) * inv * top_sims[j]; mx = fmaxf(mx, s[j]); }
    float sum = 0.f;
#pragma unroll
    for (int j = 0; j < TOPK; ++j) { s[j] = __expf(s[j] - mx); sum += s[j]; }
    float r = 1.0f / sum;
#pragma unroll
    for (int j = 0; j < TOPK; ++j) attn[(size_t)(b0 + rl) * TOPK + j] = s[j] * r;
  }
}

// ---------------- K6 (fast): 128x256 tile, 2 blocks/CU occupancy experiment ----------
// Per-wave acc[4][4] (64 regs) + frags (32) => total <=128 with __launch_bounds__(512,4)
// -> 4 waves/SIMD = 2 blocks/CU. LDS 48KB (2-deep BK=32 dbuf) -> 2 blocks fit (96KB).
// Cross-block wave overlap (m114) fills the per-half barrier/lgkmcnt drains that
// schedule variants could not (rounds 5-9: all ~267us at 1 block/CU).
union GemmSmem {
  struct { unsigned short A[2][4096]; unsigned short B[2][8192]; } s;  // 48 KB
  float ep[3456];  // epilogue alias
};

__global__ __launch_bounds__(512, 4) void k_gemm_bf(
    const unsigned short* __restrict__ A_sw, const unsigned short* __restrict__ B_sw,
    const float* __restrict__ no, const float* __restrict__ bg,
    const float* __restrict__ attn, const float* __restrict__ vb,
    const float* __restrict__ VW, float* __restrict__ out) {
  __shared__ GemmSmem sm;

  int tid = threadIdx.x;
  int lane = tid & 63, wid = tid >> 6;     // 8 waves
  int fr = lane & 15, fg = lane >> 4;
  int wr = wid >> 2, wc = wid & 3;          // 2 (M) x 4 (N); per-wave 64x64 out

  int id = blockIdx.x;                      // 1024 blocks
  int mt = (id & 7) * 16 + (id >> 6);       // XCD-pinned A row-panel (mt 0..127)
  int nt = (id >> 3) & 7;                   // nt swept 0..7 within the XCD
  int brow = mt * 128, bcol = nt * 256;

  f32x4 acc[4][4];
#pragma unroll
  for (int m = 0; m < 4; ++m)
#pragma unroll
    for (int n = 0; n < 4; ++n) acc[m][n] = (f32x4){0.f, 0.f, 0.f, 0.f};

  // staging pointers: A seg rh=wid (8 segs); B segs wid*2, wid*2+1 (16 segs).
  // Segment addr = rowhi*32768 + h*512 elems (h = K-half index 0..63).
  const unsigned short* gA  = A_sw + ((size_t)(mt * 8  + wid) << 15) + lane * 8;
  const unsigned short* gB0 = B_sw + ((size_t)(nt * 16 + wid * 2) << 15) + lane * 8;
  const unsigned short* gB1 = gB0 + 32768;
  unsigned short* lA  = sm.s.A[0] + wid * 512;
  unsigned short* lB0 = sm.s.B[0] + wid * 1024;
  unsigned short* lB1 = lB0 + 512;

  // prologue: stage half 0 into buf 0
  gload16(gA, lA); gload16(gB0, lB0); gload16(gB1, lB1);
  gA += 512; gB0 += 512; gB1 += 512;
  asm volatile("s_waitcnt vmcnt(0)" ::: "memory");
  __builtin_amdgcn_s_barrier();

  s16x8 af[4], bfr[4];
  int rdo = fg * 128 + fr * 8;
  for (int h = 0; h < 64; ++h) {
    int bh = h & 1;
    const unsigned short* Ab = sm.s.A[bh];
    const unsigned short* Bb = sm.s.B[bh];

#pragma unroll
    for (int m = 0; m < 4; ++m) af[m]  = *(const s16x8*)(Ab + (wr*4 + m) * 512 + rdo);
#pragma unroll
    for (int n = 0; n < 4; ++n) bfr[n] = *(const s16x8*)(Bb + (wc*4 + n) * 512 + rdo);
    if (h < 63) {
      unsigned short* nA  = sm.s.A[bh ^ 1] + wid * 512;
      unsigned short* nB0 = sm.s.B[bh ^ 1] + wid * 1024;
      gload16(gA, nA); gload16(gB0, nB0); gload16(gB1, nB0 + 512);
      gA += 512; gB0 += 512; gB1 += 512;
    }
    __builtin_amdgcn_s_barrier();
    asm volatile("s_waitcnt lgkmcnt(0)" ::: "memory");
    __builtin_amdgcn_sched_barrier(0);
    __builtin_amdgcn_s_setprio(1);
#pragma unroll
    for (int n = 0; n < 4; ++n)
#pragma unroll
      for (int m = 0; m < 4; ++m)
        acc[m][n] = __builtin_amdgcn_mfma_f32_16x16x32_bf16(af[m], bfr[n], acc[m][n], 0, 0, 0);
    __builtin_amdgcn_s_setprio(0);
    asm volatile("s_waitcnt vmcnt(0)" ::: "memory");   // next half's 3 loads landed
    __builtin_amdgcn_s_barrier();
  }

  // epilogue staging (aliases LDS; after final barrier all counts drained)
  for (int x = tid; x < 640; x += 512) sm.ep[x] = attn[(size_t)brow * TOPK + x];
  for (int x = tid; x < 1280; x += 512) { int j = x >> 8, c = x & 255; sm.ep[640 + x]  = VW[j*D + bcol + c]; }
  for (int x = tid; x < 1280; x += 512) { int j = x >> 8, c = x & 255; sm.ep[1920 + x] = vb[j*D + bcol + c]; }
  if (tid < 256) sm.ep[3200 + tid] = bg[bcol + tid];
  __syncthreads();

#pragma unroll
  for (int m = 0; m < 4; ++m) {
    int rbase = wr * 64 + m * 16 + fg * 4;
#pragma unroll
    for (int n = 0; n < 4; ++n) {
      int c = wc * 64 + n * 16 + fr;
      float vw0 = sm.ep[640 + 0*256 + c], vw1 = sm.ep[640 + 1*256 + c], vw2 = sm.ep[640 + 2*256 + c],
            vw3 = sm.ep[640 + 3*256 + c], vw4 = sm.ep[640 + 4*256 + c];
      float v0 = sm.ep[1920 + 0*256 + c], v1 = sm.ep[1920 + 1*256 + c], v2 = sm.ep[1920 + 2*256 + c],
            v3 = sm.ep[1920 + 3*256 + c], v4 = sm.ep[1920 + 4*256 + c];
      float bgc = sm.ep[3200 + c];
#pragma unroll
      for (int i = 0; i < 4; ++i) {
        int r = rbase + i;
        float a0 = sm.ep[r*5+0], a1 = sm.ep[r*5+1], a2 = sm.ep[r*5+2], a3 = sm.ep[r*5+3], a4 = sm.ep[r*5+4];
        float gl = acc[m][n][i] + bgc + a0*vw0 + a1*vw1 + a2*vw2 + a3*vw3 + a4*vw4;
        float att = a0*v0 + a1*v1 + a2*v2 + a3*v3 + a4*v4;
        float gate = 1.0f / (1.0f + __expf(-gl));
        size_t gi = (size_t)(brow + r) * D + bcol + c;
        float nv = __builtin_nontemporal_load(&no[gi]);
        __builtin_nontemporal_store(nv + gate * att, &out[gi]);
      }
    }
  }
}

// ---------------- K6 (fallback): f32-staging GEMM ----------------
#define BM 128
#define BN 128
#define BKf 32
#define LDK (BKf + 8)

__global__ __launch_bounds__(256) void k_gemm_f32(
    const float* __restrict__ no, const float* __restrict__ Wg,
    const float* __restrict__ bg, const float* __restrict__ attn,
    const float* __restrict__ vb, const float* __restrict__ VW,
    float* __restrict__ out) {
  __shared__ unsigned short As[BM * LDK];
  __shared__ unsigned short Bs[BN * LDK];
  __shared__ float ep[2048];

  int tid = threadIdx.x;
  int lane = tid & 63, wid = tid >> 6;
  int brow = blockIdx.x * BM;
  int bcol = blockIdx.y * BN;
  int wr = wid >> 1, wc = wid & 1;

  f32x4 acc[4][4];
#pragma unroll
  for (int m = 0; m < 4; ++m)
#pragma unroll
    for (int n = 0; n < 4; ++n) acc[m][n] = (f32x4){0.f, 0.f, 0.f, 0.f};

  int fr = lane & 15, fg = lane >> 4;

  for (int kt = 0; kt < D / BKf; ++kt) {
    int k0 = kt * BKf;
#pragma unroll
    for (int i = 0; i < 4; ++i) {
      int fid = tid + i * 256;
      int row = fid >> 3, c4 = (fid & 7) * 4;
      f32x4 a4 = *(const f32x4*)(no + (size_t)(brow + row) * D + k0 + c4);
      f32x4 b4 = *(const f32x4*)(Wg + (size_t)(bcol + row) * (2 * D) + k0 + c4);
      u16x4 ab, bb;
      ab[0] = f2bf(a4[0]); ab[1] = f2bf(a4[1]); ab[2] = f2bf(a4[2]); ab[3] = f2bf(a4[3]);
      bb[0] = f2bf(b4[0]); bb[1] = f2bf(b4[1]); bb[2] = f2bf(b4[2]); bb[3] = f2bf(b4[3]);
      *(u16x4*)(&As[row * LDK + c4]) = ab;
      *(u16x4*)(&Bs[row * LDK + c4]) = bb;
    }
    __syncthreads();
    s16x8 af[4], bfr[4];
#pragma unroll
    for (int m = 0; m < 4; ++m) af[m] = *(const s16x8*)(&As[(wr*64 + m*16 + fr) * LDK + fg*8]);
#pragma unroll
    for (int n = 0; n < 4; ++n) bfr[n] = *(const s16x8*)(&Bs[(wc*64 + n*16 + fr) * LDK + fg*8]);
#pragma unroll
    for (int m = 0; m < 4; ++m)
#pragma unroll
      for (int n = 0; n < 4; ++n)
        acc[m][n] = __builtin_amdgcn_mfma_f32_16x16x32_bf16(af[m], bfr[n], acc[m][n], 0, 0, 0);
    __syncthreads();
  }

  for (int x = tid; x < 640; x += 256) ep[x] = attn[(size_t)brow * TOPK + x];
  for (int x = tid; x < 640; x += 256) { int j = x >> 7, c = x & 127; ep[640 + x]  = VW[j*D + bcol + c]; }
  for (int x = tid; x < 640; x += 256) { int j = x >> 7, c = x & 127; ep[1280 + x] = vb[j*D + bcol + c]; }
  if (tid < 128) ep[1920 + tid] = bg[bcol + tid];
  __syncthreads();

#pragma unroll
  for (int m = 0; m < 4; ++m) {
    int rbase = wr * 64 + m * 16 + fg * 4;
#pragma unroll
    for (int n = 0; n < 4; ++n) {
      int c = wc * 64 + n * 16 + fr;
      float vw0 = ep[640 + 0*128 + c], vw1 = ep[640 + 1*128 + c], vw2 = ep[640 + 2*128 + c],
            vw3 = ep[640 + 3*128 + c], vw4 = ep[640 + 4*128 + c];
      float v0 = ep[1280 + 0*128 + c], v1 = ep[1280 + 1*128 + c], v2 = ep[1280 + 2*128 + c],
            v3 = ep[1280 + 3*128 + c], v4 = ep[1280 + 4*128 + c];
      float bgc = ep[1920 + c];
#pragma unroll
      for (int i = 0; i < 4; ++i) {
        int r = rbase + i;
        float a0 = ep[r*5+0], a1 = ep[r*5+1], a2 = ep[r*5+2], a3 = ep[r*5+3], a4 = ep[r*5+4];
        float gl = acc[m][n][i] + bgc + a0*vw0 + a1*vw1 + a2*vw2 + a3*vw3 + a4*vw4;
        float att = a0*v0 + a1*v1 + a2*v2 + a3*v3 + a4*v4;
        float gate = 1.0f / (1.0f + __expf(-gl));
        size_t gi = (size_t)(brow + r) * D + bcol + c;
        out[gi] = no[gi] + gate * att;
      }
    }
  }
}

extern "C" void kernel_launch(void* const* d_in, const int* in_sizes, int n_in,
                              void* d_out, int out_size, void* d_ws, size_t ws_size,
                              hipStream_t stream) {
  (void)in_sizes; (void)n_in; (void)out_size;
  const float* no    = (const float*)d_in[0];
  const float* ce    = (const float*)d_in[1];
  const float* bank  = (const float*)d_in[2];
  const float* mvals = (const float*)d_in[3];
  const float* Wq    = (const float*)d_in[4];
  const float* bq    = (const float*)d_in[5];
  const float* Wk    = (const float*)d_in[6];
  const float* bk    = (const float*)d_in[7];
  const float* Wv    = (const float*)d_in[8];
  const float* bvp   = (const float*)d_in[9];
  const float* Wg    = (const float*)d_in[10];
  const float* bg    = (const float*)d_in[11];
  float* out = (float*)d_out;

  char* ws = (char*)d_ws;
  float* sims     = (float*)(ws + 16384);
  float* top_sims = (float*)(ws + 220160);
  int*   top_idx  = (int*)  (ws + 220192);
  float* sbias    = (float*)(ws + 220224);
  float* kb       = (float*)(ws + 221184);
  float* vb       = (float*)(ws + 262144);
  float* VW       = (float*)(ws + 303104);
  float* KQpart   = (float*)(ws + 344064);
  float* KQ       = (float*)(ws + 1654784);
  float* attn     = (float*)(ws + 1695744);
  unsigned short* A_sw = (unsigned short*)(ws + 4194304);
  unsigned short* B_sw = (unsigned short*)(ws + 4194304 + (size_t)B_ROWS * D * 2);

  const size_t ws_need = 4194304 + (size_t)B_ROWS * D * 2 + (size_t)D * D * 2;
  const bool fast = ws_size >= ws_need;

  k_sims<<<1024, 256, 0, stream>>>(bank, ce, sims);
  k_topk<<<1, 256, 0, stream>>>(sims, top_sims, top_idx);
  k_kv<<<512, 256, 0, stream>>>(mvals, top_idx, Wk, bk, Wv, bvp, kb, vb);
  k_prep<<<fast ? 801 : 769, 256, 0, stream>>>(Wq, bq, Wg, kb, vb, KQpart, VW, sbias, B_sw);
  k_red<<<40, 256, 0, stream>>>(KQpart, KQ);
  if (fast) {
    k_attn<true><<<256, 256, 0, stream>>>(no, KQ, sbias, top_sims, attn, A_sw);
    k_gemm_bf<<<1024, 512, 0, stream>>>(A_sw, B_sw, no, bg, attn, vb, VW, out);
  } else {
    k_attn<false><<<256, 256, 0, stream>>>(no, KQ, sbias, top_sims, attn, A_sw);
    k_gemm_f32<<<dim3(B_ROWS / BM, D / BN), 256, 0, stream>>>(no, Wg, bg, attn, vb, VW, out);
  }
}

// Round 11
// 599.404 us; speedup vs baseline: 1.1044x; 1.1044x over previous
//
#include <hip/hip_runtime.h>
#include <hip/hip_bf16.h>
#include <math.h>

#define D 2048
#define M_ROWS 50000
#define B_ROWS 16384
#define TOPK 5
#define EPSN 1e-12f

typedef __attribute__((ext_vector_type(4))) float f32x4;
typedef __attribute__((ext_vector_type(8))) short s16x8;
typedef __attribute__((ext_vector_type(4))) unsigned short u16x4;

__device__ __forceinline__ unsigned short f2bf(float f) {
  union { float f; unsigned int u; } x; x.f = f;
  unsigned int u = x.u;
  unsigned int r = u + 0x7fffu + ((u >> 16) & 1u);
  return (unsigned short)(r >> 16);
}

__device__ __forceinline__ float bf2f(unsigned short b) {
  union { unsigned int u; float f; } x; x.u = ((unsigned int)b) << 16;
  return x.f;
}

__device__ __forceinline__ void gload16(const void* g, void* l) {
  __builtin_amdgcn_global_load_lds(
      (const __attribute__((address_space(1))) unsigned int*)g,
      (__attribute__((address_space(3))) unsigned int*)l, 16, 0, 0);
}

// Subtiled bf16 layout for A_sw/B_sw, per 16-row x 64-K block (2048 elems):
//   addr(row,k) = (row>>4)*32768 + (k>>6)*1024 + ((k>>5)&1)*512 + ((k>>3)&3)*128 + (row&15)*8 + (k&7)
// Wave-contiguous 1KB segments; zero bank conflicts; global_load_lds linear-dest OK.

// ---------------- K1: sims over memory bank (qnorm fused per-block) ----------------
__global__ void k_sims(const float* __restrict__ bank, const float* __restrict__ ce,
                       float* __restrict__ sims) {
  __shared__ float qs[D];
  __shared__ float red[256];
  int tid = threadIdx.x;
  float s = 0.f;
  for (int t = tid; t < D; t += 256) { float x = ce[t]; s += x * x; }
  red[tid] = s; __syncthreads();
  for (int w = 128; w > 0; w >>= 1) { if (tid < w) red[tid] += red[tid + w]; __syncthreads(); }
  float qinv = 1.0f / fmaxf(sqrtf(red[0]), EPSN);
  for (int t = tid; t < D; t += 256) qs[t] = ce[t] * qinv;
  __syncthreads();
  int lane = tid & 63, wid = tid >> 6;
  int gw = (blockIdx.x << 2) + wid;
  int nw = gridDim.x << 2;
  for (int m = gw; m < M_ROWS; m += nw) {
    const float* row = bank + (size_t)m * D;
    float dot = 0.f, sq = 0.f;
#pragma unroll
    for (int i = 0; i < 8; ++i) {
      int off = i * 256 + lane * 4;
      f32x4 a = *(const f32x4*)(row + off);
      f32x4 q = *(const f32x4*)(qs + off);
      dot += a[0]*q[0] + a[1]*q[1] + a[2]*q[2] + a[3]*q[3];
      sq  += a[0]*a[0] + a[1]*a[1] + a[2]*a[2] + a[3]*a[3];
    }
    for (int off = 32; off; off >>= 1) {
      dot += __shfl_xor(dot, off, 64);
      sq  += __shfl_xor(sq,  off, 64);
    }
    if (lane == 0) sims[m] = dot / fmaxf(sqrtf(sq), EPSN);
  }
}

// ---------------- K2: top-5 ----------------
__global__ void k_topk(const float* __restrict__ sims, float* __restrict__ top_sims,
                       int* __restrict__ top_idx) {
  __shared__ float sval[256 * TOPK];
  __shared__ int   sidx[256 * TOPK];
  __shared__ float sv2[64 * TOPK];
  __shared__ int   si2[64 * TOPK];
  int tid = threadIdx.x;
  float lv[TOPK]; int li[TOPK];
#pragma unroll
  for (int j = 0; j < TOPK; ++j) { lv[j] = -INFINITY; li[j] = 0x7fffffff; }
  for (int m = tid; m < M_ROWS; m += 256) {
    float v = sims[m];
    if (v > lv[TOPK-1] || (v == lv[TOPK-1] && m < li[TOPK-1])) {
      lv[TOPK-1] = v; li[TOPK-1] = m;
#pragma unroll
      for (int j = TOPK-1; j > 0; --j) {
        bool sw = (lv[j] > lv[j-1]) || (lv[j] == lv[j-1] && li[j] < li[j-1]);
        if (sw) { float tv=lv[j]; lv[j]=lv[j-1]; lv[j-1]=tv; int ti=li[j]; li[j]=li[j-1]; li[j-1]=ti; }
      }
    }
  }
#pragma unroll
  for (int j = 0; j < TOPK; ++j) { sval[tid*TOPK+j] = lv[j]; sidx[tid*TOPK+j] = li[j]; }
  __syncthreads();
  if (tid < 64) {
    float bv[TOPK]; int bi[TOPK];
    for (int j = 0; j < TOPK; ++j) { bv[j] = -INFINITY; bi[j] = 0x7fffffff; }
    for (int c = tid * 20; c < tid * 20 + 20; ++c) {
      float v = sval[c]; int i = sidx[c];
      if (v > bv[TOPK-1] || (v == bv[TOPK-1] && i < bi[TOPK-1])) {
        bv[TOPK-1] = v; bi[TOPK-1] = i;
        for (int j = TOPK-1; j > 0; --j) {
          bool sw = (bv[j] > bv[j-1]) || (bv[j] == bv[j-1] && bi[j] < bi[j-1]);
          if (sw) { float tv=bv[j]; bv[j]=bv[j-1]; bv[j-1]=tv; int ti=bi[j]; bi[j]=bi[j-1]; bi[j-1]=ti; }
        }
      }
    }
    for (int j = 0; j < TOPK; ++j) { sv2[tid*TOPK+j] = bv[j]; si2[tid*TOPK+j] = bi[j]; }
  }
  __syncthreads();
  if (tid == 0) {
    float bvv[TOPK]; int bii[TOPK];
    for (int j = 0; j < TOPK; ++j) { bvv[j] = -INFINITY; bii[j] = 0x7fffffff; }
    for (int c = 0; c < 64 * TOPK; ++c) {
      float v = sv2[c]; int i = si2[c];
      if (v > bvv[TOPK-1] || (v == bvv[TOPK-1] && i < bii[TOPK-1])) {
        bvv[TOPK-1] = v; bii[TOPK-1] = i;
        for (int j = TOPK-1; j > 0; --j) {
          bool sw = (bvv[j] > bvv[j-1]) || (bvv[j] == bvv[j-1] && bii[j] < bii[j-1]);
          if (sw) { float tv=bvv[j]; bvv[j]=bvv[j-1]; bvv[j-1]=tv; int ti=bii[j]; bii[j]=bii[j-1]; bii[j-1]=ti; }
        }
      }
    }
    for (int j = 0; j < TOPK; ++j) { top_sims[j] = bvv[j]; top_idx[j] = bii[j]; }
  }
}

// ---------------- K3: k,v = memories @ Wk/Wv^T + b ----------------
__global__ void k_kv(const float* __restrict__ mvals, const int* __restrict__ top_idx,
                     const float* __restrict__ Wk, const float* __restrict__ bk,
                     const float* __restrict__ Wv, const float* __restrict__ bvp,
                     float* __restrict__ kb, float* __restrict__ vb) {
  __shared__ float mem[TOPK][D];
  int tid = threadIdx.x;
  for (int j = 0; j < TOPK; ++j) {
    const float* src = mvals + (size_t)top_idx[j] * D;
    for (int t = tid; t < D; t += 256) mem[j][t] = src[t];
  }
  __syncthreads();
  int lane = tid & 63, wid = tid >> 6;
  int c = blockIdx.x * 4 + wid;
  const float* wkr = Wk + (size_t)c * D;
  const float* wvr = Wv + (size_t)c * D;
  float ak[TOPK] = {0,0,0,0,0}, av[TOPK] = {0,0,0,0,0};
#pragma unroll 2
  for (int i = 0; i < 8; ++i) {
    int off = i * 256 + lane * 4;
    f32x4 wk4 = *(const f32x4*)(wkr + off);
    f32x4 wv4 = *(const f32x4*)(wvr + off);
#pragma unroll
    for (int j = 0; j < TOPK; ++j) {
      f32x4 mv = *(const f32x4*)(&mem[j][off]);
      ak[j] += mv[0]*wk4[0] + mv[1]*wk4[1] + mv[2]*wk4[2] + mv[3]*wk4[3];
      av[j] += mv[0]*wv4[0] + mv[1]*wv4[1] + mv[2]*wv4[2] + mv[3]*wv4[3];
    }
  }
  for (int off = 32; off; off >>= 1) {
#pragma unroll
    for (int j = 0; j < TOPK; ++j) {
      ak[j] += __shfl_xor(ak[j], off, 64);
      av[j] += __shfl_xor(av[j], off, 64);
    }
  }
  if (lane == 0) {
#pragma unroll
    for (int j = 0; j < TOPK; ++j) { kb[j*D + c] = ak[j] + bk[c]; vb[j*D + c] = av[j] + bvp[c]; }
  }
}

// ---------------- K4: prep — KQ partials, VW, sbias, WgA bf16 cast (wave-coalesced) ----
__global__ void k_prep(const float* __restrict__ Wq, const float* __restrict__ bq,
                       const float* __restrict__ Wg,
                       const float* __restrict__ kb, const float* __restrict__ vb,
                       float* __restrict__ KQpart, float* __restrict__ VW,
                       float* __restrict__ sbias, unsigned short* __restrict__ B_sw) {
  __shared__ float sh[TOPK * D];
  int tid = threadIdx.x;
  int bid = blockIdx.x;
  if (bid < 256) {
    int cc = bid >> 3, tc = bid & 7;
    for (int x = tid; x < TOPK * 64; x += 256) sh[x] = kb[(x >> 6) * D + cc * 64 + (x & 63)];
    __syncthreads();
    float acc[TOPK] = {0,0,0,0,0};
    const float* wq = Wq + (size_t)(cc * 64) * D + tc * 256 + tid;
#pragma unroll 4
    for (int c = 0; c < 64; ++c) {
      float w = wq[(size_t)c * D];
#pragma unroll
      for (int j = 0; j < TOPK; ++j) acc[j] += sh[j * 64 + c] * w;
    }
#pragma unroll
    for (int j = 0; j < TOPK; ++j)
      KQpart[(size_t)(cc * TOPK + j) * D + tc * 256 + tid] = acc[j];
  } else if (bid < 768) {
    for (int x = tid; x < TOPK * D; x += 256) sh[x] = vb[x];
    __syncthreads();
    int lane = tid & 63, wid = tid >> 6;
    int c = (bid - 256) * 4 + wid;
    const float* wg = Wg + (size_t)c * (2 * D) + D;
    float acc[TOPK] = {0,0,0,0,0};
#pragma unroll 2
    for (int i = 0; i < 8; ++i) {
      int off = i * 256 + lane * 4;
      f32x4 g4 = *(const f32x4*)(wg + off);
#pragma unroll
      for (int j = 0; j < TOPK; ++j) {
        f32x4 vv = *(const f32x4*)(&sh[j*D + off]);
        acc[j] += vv[0]*g4[0] + vv[1]*g4[1] + vv[2]*g4[2] + vv[3]*g4[3];
      }
    }
    for (int off = 32; off; off >>= 1)
#pragma unroll
      for (int j = 0; j < TOPK; ++j) acc[j] += __shfl_xor(acc[j], off, 64);
    if (lane == 0)
      for (int j = 0; j < TOPK; ++j) VW[j*D + c] = acc[j];
  } else if (bid == 768) {
    for (int j = 0; j < TOPK; ++j) {
      float s = 0.f;
      for (int t = tid; t < D; t += 256) s += bq[t] * kb[j*D + t];
      sh[tid] = s; __syncthreads();
      for (int w = 128; w > 0; w >>= 1) { if (tid < w) sh[tid] += sh[tid + w]; __syncthreads(); }
      if (tid == 0) sbias[j] = sh[0];
      __syncthreads();
    }
  } else {
    int lane = tid & 63, wid = tid >> 6;
    int r0 = ((bid - 769) * 4 + wid) * 16;
    int rl = lane & 15, kg = lane >> 4;
    const float* src = Wg + (size_t)(r0 + rl) * (2 * D);
    size_t wbase = ((size_t)(r0 >> 4)) << 15;
#pragma unroll 4
    for (int it = 0; it < 64; ++it) {
      int k = it * 32 + kg * 8;
      f32x4 a = *(const f32x4*)(src + k);
      f32x4 b = *(const f32x4*)(src + k + 4);
      s16x8 p;
      p[0]=(short)f2bf(a[0]); p[1]=(short)f2bf(a[1]); p[2]=(short)f2bf(a[2]); p[3]=(short)f2bf(a[3]);
      p[4]=(short)f2bf(b[0]); p[5]=(short)f2bf(b[1]); p[6]=(short)f2bf(b[2]); p[7]=(short)f2bf(b[3]);
      *(s16x8*)(B_sw + wbase + ((size_t)it << 9) + lane * 8) = p;
    }
  }
}

// ---------------- K4b: reduce 32 KQ partials -> KQ ----------------
__global__ void k_red(const float* __restrict__ KQpart, float* __restrict__ KQ) {
  int x = blockIdx.x * 256 + threadIdx.x;
  float s = 0.f;
#pragma unroll 8
  for (int cc = 0; cc < 32; ++cc) s += KQpart[(size_t)cc * (TOPK * D) + x];
  KQ[x] = s;
}

// ---------------- K5: scores + softmax + fused no->bf16 subtiled coalesced cast ------
template <bool WRITE_CAST>
__global__ void k_attn(const float* __restrict__ no, const float* __restrict__ KQ,
                       const float* __restrict__ sbias, const float* __restrict__ top_sims,
                       float* __restrict__ attn, unsigned short* __restrict__ A_sw) {
  __shared__ float kq[TOPK * D];
  int tid = threadIdx.x;
  for (int x = tid; x < TOPK * D; x += 256) kq[x] = KQ[x];
  __syncthreads();
  int lane = tid & 63, wid = tid >> 6;
  int b0 = (blockIdx.x * 4 + wid) * 16;
  int rl = lane & 15, kg = lane >> 4;
  const float* row = no + (size_t)(b0 + rl) * D;
  size_t wbase = ((size_t)(b0 >> 4)) << 15;
  float acc[TOPK] = {0, 0, 0, 0, 0};
#pragma unroll 4
  for (int it = 0; it < 64; ++it) {
    int k = it * 32 + kg * 8;
    f32x4 a = __builtin_nontemporal_load((const f32x4*)(row + k));
    f32x4 b = __builtin_nontemporal_load((const f32x4*)(row + k + 4));
#pragma unroll
    for (int j = 0; j < TOPK; ++j) {
      f32x4 ka = *(const f32x4*)(&kq[j * D + k]);
      f32x4 kb2 = *(const f32x4*)(&kq[j * D + k + 4]);
      acc[j] += a[0]*ka[0] + a[1]*ka[1] + a[2]*ka[2] + a[3]*ka[3]
              + b[0]*kb2[0] + b[1]*kb2[1] + b[2]*kb2[2] + b[3]*kb2[3];
    }
    if (WRITE_CAST) {
      s16x8 p;
      p[0]=(short)f2bf(a[0]); p[1]=(short)f2bf(a[1]); p[2]=(short)f2bf(a[2]); p[3]=(short)f2bf(a[3]);
      p[4]=(short)f2bf(b[0]); p[5]=(short)f2bf(b[1]); p[6]=(short)f2bf(b[2]); p[7]=(short)f2bf(b[3]);
      *(s16x8*)(A_sw + wbase + ((size_t)it << 9) + lane * 8) = p;
    }
  }
#pragma unroll
  for (int j = 0; j < TOPK; ++j) {
    acc[j] += __shfl_xor(acc[j], 16, 64);
    acc[j] += __shfl_xor(acc[j], 32, 64);
  }
  if (lane < 16) {
    const float inv = 0.02209708691207961f;  // 1/sqrt(2048)
    float s[TOPK], mx = -INFINITY;
#pragma unroll
    for (int j = 0; j < TOPK; ++j) { s[j] = (acc[j] + sbias[j]) * inv * top_sims[j]; mx = fmaxf(mx, s[j]); }
    float sum = 0.f;
#pragma unroll
    for (int j = 0; j < TOPK; ++j) { s[j] = __expf(s[j] - mx); sum += s[j]; }
    float r = 1.0f / sum;
#pragma unroll
    for (int j = 0; j < TOPK; ++j) attn[(size_t)(b0 + rl) * TOPK + j] = s[j] * r;
  }
}

// ---------------- K6 (fast): 256x256, round-5 compiler-scheduled 2-phase dbuf --------
// Best-measured structure (round 5: 258us). Plain __syncthreads; compiler inserts
// fine-grained waitcnts and interleaves ds_read with MFMA. XCD-pinned mt (A panel
// L2-resident). Epilogue reads bf16 `no` from A_sw (same element: no[r][c], c<2048)
// instead of f32 `no` from HBM — removes 128MB of serialized epilogue HBM reads.
union GemmSmem {
  struct { unsigned short A[2][16384]; unsigned short B[2][16384]; } s;  // 128 KB
  float ep[4096];  // 16 KB epilogue alias (after final barrier)
};

__global__ __launch_bounds__(512, 1) void k_gemm_bf(
    const unsigned short* __restrict__ A_sw, const unsigned short* __restrict__ B_sw,
    const float* __restrict__ bg, const float* __restrict__ attn,
    const float* __restrict__ vb, const float* __restrict__ VW,
    float* __restrict__ out) {
  __shared__ GemmSmem sm;

  int tid = threadIdx.x;
  int lane = tid & 63, wid = tid >> 6;     // 8 waves
  int fr = lane & 15, fg = lane >> 4;
  int wr = wid >> 2, wc = wid & 3;          // 2 (M) x 4 (N); per-wave 128x64 out
  int rh0 = wid * 2, rh1 = wid * 2 + 1;     // staging rowhi segments per wave

  int id = blockIdx.x;                      // 512 blocks
  int mt = (id & 7) * 8 + (id >> 6);        // XCD-pinned A row-panel
  int nt = (id >> 3) & 7;                   // nt swept 0..7 within the XCD
  int brow = mt * 256, bcol = nt * 256;
  int rbA = mt * 16, rbB = nt * 16;

  f32x4 acc[8][4];
#pragma unroll
  for (int m = 0; m < 8; ++m)
#pragma unroll
    for (int n = 0; n < 4; ++n) acc[m][n] = (f32x4){0.f, 0.f, 0.f, 0.f};

  // per-wave staging sources (tile kt: +kt*1024 elems; 2 halves contiguous)
  const unsigned short* gA0 = A_sw + ((size_t)(rbA + rh0) << 15) + lane * 8;
  const unsigned short* gA1 = A_sw + ((size_t)(rbA + rh1) << 15) + lane * 8;
  const unsigned short* gB0 = B_sw + ((size_t)(rbB + rh0) << 15) + lane * 8;
  const unsigned short* gB1 = B_sw + ((size_t)(rbB + rh1) << 15) + lane * 8;

#define STG(b_) do {                                                      \
    gload16(gA0,       sm.s.A[b_] + rh0 * 1024);                          \
    gload16(gA0 + 512, sm.s.A[b_] + rh0 * 1024 + 512);                    \
    gload16(gA1,       sm.s.A[b_] + rh1 * 1024);                          \
    gload16(gA1 + 512, sm.s.A[b_] + rh1 * 1024 + 512);                    \
    gload16(gB0,       sm.s.B[b_] + rh0 * 1024);                          \
    gload16(gB0 + 512, sm.s.B[b_] + rh0 * 1024 + 512);                    \
    gload16(gB1,       sm.s.B[b_] + rh1 * 1024);                          \
    gload16(gB1 + 512, sm.s.B[b_] + rh1 * 1024 + 512);                    \
    gA0 += 1024; gA1 += 1024; gB0 += 1024; gB1 += 1024;                   \
  } while (0)

  // prologue: stage tile 0 into buf 0
  STG(0);
  __syncthreads();

  int rdo = fg * 128 + fr * 8;
  for (int kt = 0; kt < 32; ++kt) {
    int b = kt & 1;
    if (kt < 31) STG(b ^ 1);
    const unsigned short* Ab = sm.s.A[b];
    const unsigned short* Bb = sm.s.B[b];
#pragma unroll
    for (int kk = 0; kk < 2; ++kk) {
      s16x8 af[8], bfr[4];
#pragma unroll
      for (int m = 0; m < 8; ++m) af[m]  = *(const s16x8*)(Ab + (wr*8 + m) * 1024 + kk * 512 + rdo);
#pragma unroll
      for (int n = 0; n < 4; ++n) bfr[n] = *(const s16x8*)(Bb + (wc*4 + n) * 1024 + kk * 512 + rdo);
#pragma unroll
      for (int n = 0; n < 4; ++n)
#pragma unroll
        for (int m = 0; m < 8; ++m)
          acc[m][n] = __builtin_amdgcn_mfma_f32_16x16x32_bf16(af[m], bfr[n], acc[m][n], 0, 0, 0);
    }
    __syncthreads();  // drains vmcnt(0): next-tile loads landed; all reads of b done
  }

  // epilogue staging (aliases LDS; after final barrier all counts drained)
  for (int x = tid; x < 1280; x += 512) sm.ep[x] = attn[(size_t)brow * TOPK + x];
  for (int x = tid; x < 1280; x += 512) { int j = x >> 8, c = x & 255; sm.ep[1280 + x] = VW[j*D + bcol + c]; }
  for (int x = tid; x < 1280; x += 512) { int j = x >> 8, c = x & 255; sm.ep[2560 + x] = vb[j*D + bcol + c]; }
  if (tid < 256) sm.ep[3840 + tid] = bg[bcol + tid];
  __syncthreads();

#pragma unroll
  for (int m = 0; m < 8; ++m) {
    int rbase = wr * 128 + m * 16 + fg * 4;
#pragma unroll
    for (int n = 0; n < 4; ++n) {
      int c = wc * 64 + n * 16 + fr;
      float vw0 = sm.ep[1280 + 0*256 + c], vw1 = sm.ep[1280 + 1*256 + c], vw2 = sm.ep[1280 + 2*256 + c],
            vw3 = sm.ep[1280 + 3*256 + c], vw4 = sm.ep[1280 + 4*256 + c];
      float v0 = sm.ep[2560 + 0*256 + c], v1 = sm.ep[2560 + 1*256 + c], v2 = sm.ep[2560 + 2*256 + c],
            v3 = sm.ep[2560 + 3*256 + c], v4 = sm.ep[2560 + 4*256 + c];
      float bgc = sm.ep[3840 + c];
#pragma unroll
      for (int i = 0; i < 4; ++i) {
        int r = rbase + i;
        float a0 = sm.ep[r*5+0], a1 = sm.ep[r*5+1], a2 = sm.ep[r*5+2], a3 = sm.ep[r*5+3], a4 = sm.ep[r*5+4];
        float gl = acc[m][n][i] + bgc + a0*vw0 + a1*vw1 + a2*vw2 + a3*vw3 + a4*vw4;
        float att = a0*v0 + a1*v1 + a2*v2 + a3*v3 + a4*v4;
        float gate = 1.0f / (1.0f + __expf(-gl));
        int r2 = brow + r, c2 = bcol + c;
        // bf16(no[r2][c2]) from A_sw (L2-hot; c2 < 2048 so same element space as A)
        size_t na = ((size_t)(r2 >> 4) << 15) + ((size_t)(c2 >> 6) << 10)
                  + (size_t)(((c2 >> 5) & 1) * 512 + ((c2 >> 3) & 3) * 128 + (r2 & 15) * 8 + (c2 & 7));
        float nv = bf2f(A_sw[na]);
        out[(size_t)r2 * D + c2] = nv + gate * att;
      }
    }
  }
}

// ---------------- K6 (fallback): f32-staging GEMM ----------------
#define BM 128
#define BN 128
#define BKf 32
#define LDK (BKf + 8)

__global__ __launch_bounds__(256) void k_gemm_f32(
    const float* __restrict__ no, const float* __restrict__ Wg,
    const float* __restrict__ bg, const float* __restrict__ attn,
    const float* __restrict__ vb, const float* __restrict__ VW,
    float* __restrict__ out) {
  __shared__ unsigned short As[BM * LDK];
  __shared__ unsigned short Bs[BN * LDK];
  __shared__ float ep[2048];

  int tid = threadIdx.x;
  int lane = tid & 63, wid = tid >> 6;
  int brow = blockIdx.x * BM;
  int bcol = blockIdx.y * BN;
  int wr = wid >> 1, wc = wid & 1;

  f32x4 acc[4][4];
#pragma unroll
  for (int m = 0; m < 4; ++m)
#pragma unroll
    for (int n = 0; n < 4; ++n) acc[m][n] = (f32x4){0.f, 0.f, 0.f, 0.f};

  int fr = lane & 15, fg = lane >> 4;

  for (int kt = 0; kt < D / BKf; ++kt) {
    int k0 = kt * BKf;
#pragma unroll
    for (int i = 0; i < 4; ++i) {
      int fid = tid + i * 256;
      int row = fid >> 3, c4 = (fid & 7) * 4;
      f32x4 a4 = *(const f32x4*)(no + (size_t)(brow + row) * D + k0 + c4);
      f32x4 b4 = *(const f32x4*)(Wg + (size_t)(bcol + row) * (2 * D) + k0 + c4);
      u16x4 ab, bb;
      ab[0] = f2bf(a4[0]); ab[1] = f2bf(a4[1]); ab[2] = f2bf(a4[2]); ab[3] = f2bf(a4[3]);
      bb[0] = f2bf(b4[0]); bb[1] = f2bf(b4[1]); bb[2] = f2bf(b4[2]); bb[3] = f2bf(b4[3]);
      *(u16x4*)(&As[row * LDK + c4]) = ab;
      *(u16x4*)(&Bs[row * LDK + c4]) = bb;
    }
    __syncthreads();
    s16x8 af[4], bfr[4];
#pragma unroll
    for (int m = 0; m < 4; ++m) af[m] = *(const s16x8*)(&As[(wr*64 + m*16 + fr) * LDK + fg*8]);
#pragma unroll
    for (int n = 0; n < 4; ++n) bfr[n] = *(const s16x8*)(&Bs[(wc*64 + n*16 + fr) * LDK + fg*8]);
#pragma unroll
    for (int m = 0; m < 4; ++m)
#pragma unroll
      for (int n = 0; n < 4; ++n)
        acc[m][n] = __builtin_amdgcn_mfma_f32_16x16x32_bf16(af[m], bfr[n], acc[m][n], 0, 0, 0);
    __syncthreads();
  }

  for (int x = tid; x < 640; x += 256) ep[x] = attn[(size_t)brow * TOPK + x];
  for (int x = tid; x < 640; x += 256) { int j = x >> 7, c = x & 127; ep[640 + x]  = VW[j*D + bcol + c]; }
  for (int x = tid; x < 640; x += 256) { int j = x >> 7, c = x & 127; ep[1280 + x] = vb[j*D + bcol + c]; }
  if (tid < 128) ep[1920 + tid] = bg[bcol + tid];
  __syncthreads();

#pragma unroll
  for (int m = 0; m < 4; ++m) {
    int rbase = wr * 64 + m * 16 + fg * 4;
#pragma unroll
    for (int n = 0; n < 4; ++n) {
      int c = wc * 64 + n * 16 + fr;
      float vw0 = ep[640 + 0*128 + c], vw1 = ep[640 + 1*128 + c], vw2 = ep[640 + 2*128 + c],
            vw3 = ep[640 + 3*128 + c], vw4 = ep[640 + 4*128 + c];
      float v0 = ep[1280 + 0*128 + c], v1 = ep[1280 + 1*128 + c], v2 = ep[1280 + 2*128 + c],
            v3 = ep[1280 + 3*128 + c], v4 = ep[1280 + 4*128 + c];
      float bgc = ep[1920 + c];
#pragma unroll
      for (int i = 0; i < 4; ++i) {
        int r = rbase + i;
        float a0 = ep[r*5+0], a1 = ep[r*5+1], a2 = ep[r*5+2], a3 = ep[r*5+3], a4 = ep[r*5+4];
        float gl = acc[m][n][i] + bgc + a0*vw0 + a1*vw1 + a2*vw2 + a3*vw3 + a4*vw4;
        float att = a0*v0 + a1*v1 + a2*v2 + a3*v3 + a4*v4;
        float gate = 1.0f / (1.0f + __expf(-gl));
        size_t gi = (size_t)(brow + r) * D + bcol + c;
        out[gi] = no[gi] + gate * att;
      }
    }
  }
}

extern "C" void kernel_launch(void* const* d_in, const int* in_sizes, int n_in,
                              void* d_out, int out_size, void* d_ws, size_t ws_size,
                              hipStream_t stream) {
  (void)in_sizes; (void)n_in; (void)out_size;
  const float* no    = (const float*)d_in[0];
  const float* ce    = (const float*)d_in[1];
  const float* bank  = (const float*)d_in[2];
  const float* mvals = (const float*)d_in[3];
  const float* Wq    = (const float*)d_in[4];
  const float* bq    = (const float*)d_in[5];
  const float* Wk    = (const float*)d_in[6];
  const float* bk    = (const float*)d_in[7];
  const float* Wv    = (const float*)d_in[8];
  const float* bvp   = (const float*)d_in[9];
  const float* Wg    = (const float*)d_in[10];
  const float* bg    = (const float*)d_in[11];
  float* out = (float*)d_out;

  char* ws = (char*)d_ws;
  float* sims     = (float*)(ws + 16384);
  float* top_sims = (float*)(ws + 220160);
  int*   top_idx  = (int*)  (ws + 220192);
  float* sbias    = (float*)(ws + 220224);
  float* kb       = (float*)(ws + 221184);
  float* vb       = (float*)(ws + 262144);
  float* VW       = (float*)(ws + 303104);
  float* KQpart   = (float*)(ws + 344064);
  float* KQ       = (float*)(ws + 1654784);
  float* attn     = (float*)(ws + 1695744);
  unsigned short* A_sw = (unsigned short*)(ws + 4194304);
  unsigned short* B_sw = (unsigned short*)(ws + 4194304 + (size_t)B_ROWS * D * 2);

  const size_t ws_need = 4194304 + (size_t)B_ROWS * D * 2 + (size_t)D * D * 2;
  const bool fast = ws_size >= ws_need;

  k_sims<<<1024, 256, 0, stream>>>(bank, ce, sims);
  k_topk<<<1, 256, 0, stream>>>(sims, top_sims, top_idx);
  k_kv<<<512, 256, 0, stream>>>(mvals, top_idx, Wk, bk, Wv, bvp, kb, vb);
  k_prep<<<fast ? 801 : 769, 256, 0, stream>>>(Wq, bq, Wg, kb, vb, KQpart, VW, sbias, B_sw);
  k_red<<<40, 256, 0, stream>>>(KQpart, KQ);
  if (fast) {
    k_attn<true><<<256, 256, 0, stream>>>(no, KQ, sbias, top_sims, attn, A_sw);
    k_gemm_bf<<<512, 512, 0, stream>>>(A_sw, B_sw, bg, attn, vb, VW, out);
  } else {
    k_attn<false><<<256, 256, 0, stream>>>(no, KQ, sbias, top_sims, attn, A_sw);
    k_gemm_f32<<<dim3(B_ROWS / BM, D / BN), 256, 0, stream>>>(no, Wg, bg, attn, vb, VW, out);
  }
}

// Round 12
// 505.286 us; speedup vs baseline: 1.3101x; 1.1863x over previous
//
#include <hip/hip_runtime.h>
#include <hip/hip_bf16.h>
#include <math.h>

#define D 2048
#define M_ROWS 50000
#define B_ROWS 16384
#define TOPK 5
#define EPSN 1e-12f

typedef __attribute__((ext_vector_type(4))) float f32x4;
typedef __attribute__((ext_vector_type(8))) short s16x8;
typedef __attribute__((ext_vector_type(4))) unsigned short u16x4;

__device__ __forceinline__ unsigned short f2bf(float f) {
  union { float f; unsigned int u; } x; x.f = f;
  unsigned int u = x.u;
  unsigned int r = u + 0x7fffu + ((u >> 16) & 1u);
  return (unsigned short)(r >> 16);
}

__device__ __forceinline__ float bf2f(unsigned short b) {
  union { unsigned int u; float f; } x; x.u = ((unsigned int)b) << 16;
  return x.f;
}

__device__ __forceinline__ void gload16(const void* g, void* l) {
  __builtin_amdgcn_global_load_lds(
      (const __attribute__((address_space(1))) unsigned int*)g,
      (__attribute__((address_space(3))) unsigned int*)l, 16, 0, 0);
}

// Subtiled bf16 layout for A_sw/B_sw, per 16-row x 64-K block (2048 elems):
//   addr(row,k) = (row>>4)*32768 + (k>>6)*1024 + ((k>>5)&1)*512 + ((k>>3)&3)*128 + (row&15)*8 + (k&7)
// Wave-contiguous 1KB segments; zero bank conflicts; global_load_lds linear-dest OK.

// ---------------- K1: sims over memory bank (qnorm fused per-block) ----------------
__global__ void k_sims(const float* __restrict__ bank, const float* __restrict__ ce,
                       float* __restrict__ sims) {
  __shared__ float qs[D];
  __shared__ float red[256];
  int tid = threadIdx.x;
  float s = 0.f;
  for (int t = tid; t < D; t += 256) { float x = ce[t]; s += x * x; }
  red[tid] = s; __syncthreads();
  for (int w = 128; w > 0; w >>= 1) { if (tid < w) red[tid] += red[tid + w]; __syncthreads(); }
  float qinv = 1.0f / fmaxf(sqrtf(red[0]), EPSN);
  for (int t = tid; t < D; t += 256) qs[t] = ce[t] * qinv;
  __syncthreads();
  int lane = tid & 63, wid = tid >> 6;
  int gw = (blockIdx.x << 2) + wid;
  int nw = gridDim.x << 2;
  for (int m = gw; m < M_ROWS; m += nw) {
    const float* row = bank + (size_t)m * D;
    float dot = 0.f, sq = 0.f;
#pragma unroll
    for (int i = 0; i < 8; ++i) {
      int off = i * 256 + lane * 4;
      f32x4 a = *(const f32x4*)(row + off);
      f32x4 q = *(const f32x4*)(qs + off);
      dot += a[0]*q[0] + a[1]*q[1] + a[2]*q[2] + a[3]*q[3];
      sq  += a[0]*a[0] + a[1]*a[1] + a[2]*a[2] + a[3]*a[3];
    }
    for (int off = 32; off; off >>= 1) {
      dot += __shfl_xor(dot, off, 64);
      sq  += __shfl_xor(sq,  off, 64);
    }
    if (lane == 0) sims[m] = dot / fmaxf(sqrtf(sq), EPSN);
  }
}

// ---------------- K2: top-5 (1024 threads) ----------------
__global__ __launch_bounds__(1024) void k_topk(
    const float* __restrict__ sims, float* __restrict__ top_sims,
    int* __restrict__ top_idx) {
  __shared__ float sval[1024 * TOPK];
  __shared__ int   sidx[1024 * TOPK];
  __shared__ float sv2[64 * TOPK];
  __shared__ int   si2[64 * TOPK];
  int tid = threadIdx.x;
  float lv[TOPK]; int li[TOPK];
#pragma unroll
  for (int j = 0; j < TOPK; ++j) { lv[j] = -INFINITY; li[j] = 0x7fffffff; }
  for (int m = tid; m < M_ROWS; m += 1024) {
    float v = sims[m];
    if (v > lv[TOPK-1] || (v == lv[TOPK-1] && m < li[TOPK-1])) {
      lv[TOPK-1] = v; li[TOPK-1] = m;
#pragma unroll
      for (int j = TOPK-1; j > 0; --j) {
        bool sw = (lv[j] > lv[j-1]) || (lv[j] == lv[j-1] && li[j] < li[j-1]);
        if (sw) { float tv=lv[j]; lv[j]=lv[j-1]; lv[j-1]=tv; int ti=li[j]; li[j]=li[j-1]; li[j-1]=ti; }
      }
    }
  }
#pragma unroll
  for (int j = 0; j < TOPK; ++j) { sval[tid*TOPK+j] = lv[j]; sidx[tid*TOPK+j] = li[j]; }
  __syncthreads();
  if (tid < 64) {
    float bv[TOPK]; int bi[TOPK];
    for (int j = 0; j < TOPK; ++j) { bv[j] = -INFINITY; bi[j] = 0x7fffffff; }
    for (int c = tid * 80; c < tid * 80 + 80; ++c) {
      float v = sval[c]; int i = sidx[c];
      if (v > bv[TOPK-1] || (v == bv[TOPK-1] && i < bi[TOPK-1])) {
        bv[TOPK-1] = v; bi[TOPK-1] = i;
        for (int j = TOPK-1; j > 0; --j) {
          bool sw = (bv[j] > bv[j-1]) || (bv[j] == bv[j-1] && bi[j] < bi[j-1]);
          if (sw) { float tv=bv[j]; bv[j]=bv[j-1]; bv[j-1]=tv; int ti=bi[j]; bi[j]=bi[j-1]; bi[j-1]=ti; }
        }
      }
    }
    for (int j = 0; j < TOPK; ++j) { sv2[tid*TOPK+j] = bv[j]; si2[tid*TOPK+j] = bi[j]; }
  }
  __syncthreads();
  if (tid == 0) {
    float bvv[TOPK]; int bii[TOPK];
    for (int j = 0; j < TOPK; ++j) { bvv[j] = -INFINITY; bii[j] = 0x7fffffff; }
    for (int c = 0; c < 64 * TOPK; ++c) {
      float v = sv2[c]; int i = si2[c];
      if (v > bvv[TOPK-1] || (v == bvv[TOPK-1] && i < bii[TOPK-1])) {
        bvv[TOPK-1] = v; bii[TOPK-1] = i;
        for (int j = TOPK-1; j > 0; --j) {
          bool sw = (bvv[j] > bvv[j-1]) || (bvv[j] == bvv[j-1] && bii[j] < bii[j-1]);
          if (sw) { float tv=bvv[j]; bvv[j]=bvv[j-1]; bvv[j-1]=tv; int ti=bii[j]; bii[j]=bii[j-1]; bii[j-1]=ti; }
        }
      }
    }
    for (int j = 0; j < TOPK; ++j) { top_sims[j] = bvv[j]; top_idx[j] = bii[j]; }
  }
}

// ---------------- K3: k,v = memories @ Wk/Wv^T + b ----------------
__global__ void k_kv(const float* __restrict__ mvals, const int* __restrict__ top_idx,
                     const float* __restrict__ Wk, const float* __restrict__ bk,
                     const float* __restrict__ Wv, const float* __restrict__ bvp,
                     float* __restrict__ kb, float* __restrict__ vb) {
  __shared__ float mem[TOPK][D];
  int tid = threadIdx.x;
  for (int j = 0; j < TOPK; ++j) {
    const float* src = mvals + (size_t)top_idx[j] * D;
    for (int t = tid; t < D; t += 256) mem[j][t] = src[t];
  }
  __syncthreads();
  int lane = tid & 63, wid = tid >> 6;
  int c = blockIdx.x * 4 + wid;
  const float* wkr = Wk + (size_t)c * D;
  const float* wvr = Wv + (size_t)c * D;
  float ak[TOPK] = {0,0,0,0,0}, av[TOPK] = {0,0,0,0,0};
#pragma unroll 2
  for (int i = 0; i < 8; ++i) {
    int off = i * 256 + lane * 4;
    f32x4 wk4 = *(const f32x4*)(wkr + off);
    f32x4 wv4 = *(const f32x4*)(wvr + off);
#pragma unroll
    for (int j = 0; j < TOPK; ++j) {
      f32x4 mv = *(const f32x4*)(&mem[j][off]);
      ak[j] += mv[0]*wk4[0] + mv[1]*wk4[1] + mv[2]*wk4[2] + mv[3]*wk4[3];
      av[j] += mv[0]*wv4[0] + mv[1]*wv4[1] + mv[2]*wv4[2] + mv[3]*wv4[3];
    }
  }
  for (int off = 32; off; off >>= 1) {
#pragma unroll
    for (int j = 0; j < TOPK; ++j) {
      ak[j] += __shfl_xor(ak[j], off, 64);
      av[j] += __shfl_xor(av[j], off, 64);
    }
  }
  if (lane == 0) {
#pragma unroll
    for (int j = 0; j < TOPK; ++j) { kb[j*D + c] = ak[j] + bk[c]; vb[j*D + c] = av[j] + bvp[c]; }
  }
}

// ---------------- K4: prep — KQ partials, VW, sbias, WgA bf16 cast (wave-coalesced) ----
__global__ void k_prep(const float* __restrict__ Wq, const float* __restrict__ bq,
                       const float* __restrict__ Wg,
                       const float* __restrict__ kb, const float* __restrict__ vb,
                       float* __restrict__ KQpart, float* __restrict__ VW,
                       float* __restrict__ sbias, unsigned short* __restrict__ B_sw) {
  __shared__ float sh[TOPK * D];
  int tid = threadIdx.x;
  int bid = blockIdx.x;
  if (bid < 256) {
    int cc = bid >> 3, tc = bid & 7;
    for (int x = tid; x < TOPK * 64; x += 256) sh[x] = kb[(x >> 6) * D + cc * 64 + (x & 63)];
    __syncthreads();
    float acc[TOPK] = {0,0,0,0,0};
    const float* wq = Wq + (size_t)(cc * 64) * D + tc * 256 + tid;
#pragma unroll 4
    for (int c = 0; c < 64; ++c) {
      float w = wq[(size_t)c * D];
#pragma unroll
      for (int j = 0; j < TOPK; ++j) acc[j] += sh[j * 64 + c] * w;
    }
#pragma unroll
    for (int j = 0; j < TOPK; ++j)
      KQpart[(size_t)(cc * TOPK + j) * D + tc * 256 + tid] = acc[j];
  } else if (bid < 768) {
    for (int x = tid; x < TOPK * D; x += 256) sh[x] = vb[x];
    __syncthreads();
    int lane = tid & 63, wid = tid >> 6;
    int c = (bid - 256) * 4 + wid;
    const float* wg = Wg + (size_t)c * (2 * D) + D;
    float acc[TOPK] = {0,0,0,0,0};
#pragma unroll 2
    for (int i = 0; i < 8; ++i) {
      int off = i * 256 + lane * 4;
      f32x4 g4 = *(const f32x4*)(wg + off);
#pragma unroll
      for (int j = 0; j < TOPK; ++j) {
        f32x4 vv = *(const f32x4*)(&sh[j*D + off]);
        acc[j] += vv[0]*g4[0] + vv[1]*g4[1] + vv[2]*g4[2] + vv[3]*g4[3];
      }
    }
    for (int off = 32; off; off >>= 1)
#pragma unroll
      for (int j = 0; j < TOPK; ++j) acc[j] += __shfl_xor(acc[j], off, 64);
    if (lane == 0)
      for (int j = 0; j < TOPK; ++j) VW[j*D + c] = acc[j];
  } else if (bid == 768) {
    for (int j = 0; j < TOPK; ++j) {
      float s = 0.f;
      for (int t = tid; t < D; t += 256) s += bq[t] * kb[j*D + t];
      sh[tid] = s; __syncthreads();
      for (int w = 128; w > 0; w >>= 1) { if (tid < w) sh[tid] += sh[tid + w]; __syncthreads(); }
      if (tid == 0) sbias[j] = sh[0];
      __syncthreads();
    }
  } else {
    int lane = tid & 63, wid = tid >> 6;
    int r0 = ((bid - 769) * 4 + wid) * 16;
    int rl = lane & 15, kg = lane >> 4;
    const float* src = Wg + (size_t)(r0 + rl) * (2 * D);
    size_t wbase = ((size_t)(r0 >> 4)) << 15;
#pragma unroll 4
    for (int it = 0; it < 64; ++it) {
      int k = it * 32 + kg * 8;
      f32x4 a = *(const f32x4*)(src + k);
      f32x4 b = *(const f32x4*)(src + k + 4);
      s16x8 p;
      p[0]=(short)f2bf(a[0]); p[1]=(short)f2bf(a[1]); p[2]=(short)f2bf(a[2]); p[3]=(short)f2bf(a[3]);
      p[4]=(short)f2bf(b[0]); p[5]=(short)f2bf(b[1]); p[6]=(short)f2bf(b[2]); p[7]=(short)f2bf(b[3]);
      *(s16x8*)(B_sw + wbase + ((size_t)it << 9) + lane * 8) = p;
    }
  }
}

// ---------------- K5: scores + softmax + fused no->bf16 cast (8-wave, fused KQ reduce)
// 512 blocks x 512 threads; block = 32 rows = 2 rowgroups x 4 K-quarters (8 waves).
// Wave (g=wid>>2, q=wid&3): rows [b0+g*16, +16), K-its [q*16, q*16+16). Cross-wave
// dot reduction via LDS; softmax by q==0 waves. A_sw writes identical to before.
template <bool WRITE_CAST>
__global__ __launch_bounds__(512) void k_attn(
    const float* __restrict__ no, const float* __restrict__ KQpart,
    const float* __restrict__ sbias, const float* __restrict__ top_sims,
    float* __restrict__ attn, unsigned short* __restrict__ A_sw) {
  __shared__ float kq[TOPK * D];
  __shared__ float red[8][16][TOPK + 1];
  int tid = threadIdx.x;
  for (int x = tid; x < TOPK * D; x += 512) {
    float s = 0.f;
#pragma unroll 8
    for (int cc = 0; cc < 32; ++cc) s += KQpart[(size_t)cc * (TOPK * D) + x];
    kq[x] = s;
  }
  __syncthreads();
  int lane = tid & 63, wid = tid >> 6;
  int g = wid >> 2, q = wid & 3;
  int b0 = blockIdx.x * 32;
  int rl = lane & 15, kg = lane >> 4;
  int rowi = b0 + g * 16 + rl;
  const float* row = no + (size_t)rowi * D;
  size_t wbase = ((size_t)((b0 >> 4) + g)) << 15;
  float acc[TOPK] = {0, 0, 0, 0, 0};
#pragma unroll 4
  for (int it = q * 16; it < q * 16 + 16; ++it) {
    int k = it * 32 + kg * 8;
    f32x4 a = __builtin_nontemporal_load((const f32x4*)(row + k));
    f32x4 b = __builtin_nontemporal_load((const f32x4*)(row + k + 4));
#pragma unroll
    for (int j = 0; j < TOPK; ++j) {
      f32x4 ka = *(const f32x4*)(&kq[j * D + k]);
      f32x4 kb2 = *(const f32x4*)(&kq[j * D + k + 4]);
      acc[j] += a[0]*ka[0] + a[1]*ka[1] + a[2]*ka[2] + a[3]*ka[3]
              + b[0]*kb2[0] + b[1]*kb2[1] + b[2]*kb2[2] + b[3]*kb2[3];
    }
    if (WRITE_CAST) {
      s16x8 p;
      p[0]=(short)f2bf(a[0]); p[1]=(short)f2bf(a[1]); p[2]=(short)f2bf(a[2]); p[3]=(short)f2bf(a[3]);
      p[4]=(short)f2bf(b[0]); p[5]=(short)f2bf(b[1]); p[6]=(short)f2bf(b[2]); p[7]=(short)f2bf(b[3]);
      *(s16x8*)(A_sw + wbase + ((size_t)it << 9) + lane * 8) = p;
    }
  }
#pragma unroll
  for (int j = 0; j < TOPK; ++j) {
    acc[j] += __shfl_xor(acc[j], 16, 64);
    acc[j] += __shfl_xor(acc[j], 32, 64);
  }
  if (lane < 16) {
#pragma unroll
    for (int j = 0; j < TOPK; ++j) red[wid][rl][j] = acc[j];
  }
  __syncthreads();
  if (q == 0 && lane < 16) {
    const float inv = 0.02209708691207961f;  // 1/sqrt(2048)
    float s[TOPK], mx = -INFINITY;
#pragma unroll
    for (int j = 0; j < TOPK; ++j) {
      float t = red[g*4+0][rl][j] + red[g*4+1][rl][j] + red[g*4+2][rl][j] + red[g*4+3][rl][j];
      s[j] = (t + sbias[j]) * inv * top_sims[j];
      mx = fmaxf(mx, s[j]);
    }
    float sum = 0.f;
#pragma unroll
    for (int j = 0; j < TOPK; ++j) { s[j] = __expf(s[j] - mx); sum += s[j]; }
    float r = 1.0f / sum;
#pragma unroll
    for (int j = 0; j < TOPK; ++j) attn[(size_t)rowi * TOPK + j] = s[j] * r;
  }
}

// ---------------- K6 (fast): 256x256, round-5 compiler-scheduled 2-phase dbuf --------
// Plateaued structure (rounds 5-11 all ~258-270us). XCD-pinned mt; epilogue reads
// bf16 no from A_sw (L2-hot).
union GemmSmem {
  struct { unsigned short A[2][16384]; unsigned short B[2][16384]; } s;  // 128 KB
  float ep[4096];
};

__global__ __launch_bounds__(512, 1) void k_gemm_bf(
    const unsigned short* __restrict__ A_sw, const unsigned short* __restrict__ B_sw,
    const float* __restrict__ bg, const float* __restrict__ attn,
    const float* __restrict__ vb, const float* __restrict__ VW,
    float* __restrict__ out) {
  __shared__ GemmSmem sm;

  int tid = threadIdx.x;
  int lane = tid & 63, wid = tid >> 6;
  int fr = lane & 15, fg = lane >> 4;
  int wr = wid >> 2, wc = wid & 3;
  int rh0 = wid * 2, rh1 = wid * 2 + 1;

  int id = blockIdx.x;
  int mt = (id & 7) * 8 + (id >> 6);
  int nt = (id >> 3) & 7;
  int brow = mt * 256, bcol = nt * 256;
  int rbA = mt * 16, rbB = nt * 16;

  f32x4 acc[8][4];
#pragma unroll
  for (int m = 0; m < 8; ++m)
#pragma unroll
    for (int n = 0; n < 4; ++n) acc[m][n] = (f32x4){0.f, 0.f, 0.f, 0.f};

  const unsigned short* gA0 = A_sw + ((size_t)(rbA + rh0) << 15) + lane * 8;
  const unsigned short* gA1 = A_sw + ((size_t)(rbA + rh1) << 15) + lane * 8;
  const unsigned short* gB0 = B_sw + ((size_t)(rbB + rh0) << 15) + lane * 8;
  const unsigned short* gB1 = B_sw + ((size_t)(rbB + rh1) << 15) + lane * 8;

#define STG(b_) do {                                                      \
    gload16(gA0,       sm.s.A[b_] + rh0 * 1024);                          \
    gload16(gA0 + 512, sm.s.A[b_] + rh0 * 1024 + 512);                    \
    gload16(gA1,       sm.s.A[b_] + rh1 * 1024);                          \
    gload16(gA1 + 512, sm.s.A[b_] + rh1 * 1024 + 512);                    \
    gload16(gB0,       sm.s.B[b_] + rh0 * 1024);                          \
    gload16(gB0 + 512, sm.s.B[b_] + rh0 * 1024 + 512);                    \
    gload16(gB1,       sm.s.B[b_] + rh1 * 1024);                          \
    gload16(gB1 + 512, sm.s.B[b_] + rh1 * 1024 + 512);                    \
    gA0 += 1024; gA1 += 1024; gB0 += 1024; gB1 += 1024;                   \
  } while (0)

  STG(0);
  __syncthreads();

  int rdo = fg * 128 + fr * 8;
  for (int kt = 0; kt < 32; ++kt) {
    int b = kt & 1;
    if (kt < 31) STG(b ^ 1);
    const unsigned short* Ab = sm.s.A[b];
    const unsigned short* Bb = sm.s.B[b];
#pragma unroll
    for (int kk = 0; kk < 2; ++kk) {
      s16x8 af[8], bfr[4];
#pragma unroll
      for (int m = 0; m < 8; ++m) af[m]  = *(const s16x8*)(Ab + (wr*8 + m) * 1024 + kk * 512 + rdo);
#pragma unroll
      for (int n = 0; n < 4; ++n) bfr[n] = *(const s16x8*)(Bb + (wc*4 + n) * 1024 + kk * 512 + rdo);
#pragma unroll
      for (int n = 0; n < 4; ++n)
#pragma unroll
        for (int m = 0; m < 8; ++m)
          acc[m][n] = __builtin_amdgcn_mfma_f32_16x16x32_bf16(af[m], bfr[n], acc[m][n], 0, 0, 0);
    }
    __syncthreads();
  }

  for (int x = tid; x < 1280; x += 512) sm.ep[x] = attn[(size_t)brow * TOPK + x];
  for (int x = tid; x < 1280; x += 512) { int j = x >> 8, c = x & 255; sm.ep[1280 + x] = VW[j*D + bcol + c]; }
  for (int x = tid; x < 1280; x += 512) { int j = x >> 8, c = x & 255; sm.ep[2560 + x] = vb[j*D + bcol + c]; }
  if (tid < 256) sm.ep[3840 + tid] = bg[bcol + tid];
  __syncthreads();

#pragma unroll
  for (int m = 0; m < 8; ++m) {
    int rbase = wr * 128 + m * 16 + fg * 4;
#pragma unroll
    for (int n = 0; n < 4; ++n) {
      int c = wc * 64 + n * 16 + fr;
      float vw0 = sm.ep[1280 + 0*256 + c], vw1 = sm.ep[1280 + 1*256 + c], vw2 = sm.ep[1280 + 2*256 + c],
            vw3 = sm.ep[1280 + 3*256 + c], vw4 = sm.ep[1280 + 4*256 + c];
      float v0 = sm.ep[2560 + 0*256 + c], v1 = sm.ep[2560 + 1*256 + c], v2 = sm.ep[2560 + 2*256 + c],
            v3 = sm.ep[2560 + 3*256 + c], v4 = sm.ep[2560 + 4*256 + c];
      float bgc = sm.ep[3840 + c];
#pragma unroll
      for (int i = 0; i < 4; ++i) {
        int r = rbase + i;
        float a0 = sm.ep[r*5+0], a1 = sm.ep[r*5+1], a2 = sm.ep[r*5+2], a3 = sm.ep[r*5+3], a4 = sm.ep[r*5+4];
        float gl = acc[m][n][i] + bgc + a0*vw0 + a1*vw1 + a2*vw2 + a3*vw3 + a4*vw4;
        float att = a0*v0 + a1*v1 + a2*v2 + a3*v3 + a4*v4;
        float gate = 1.0f / (1.0f + __expf(-gl));
        int r2 = brow + r, c2 = bcol + c;
        size_t na = ((size_t)(r2 >> 4) << 15) + ((size_t)(c2 >> 6) << 10)
                  + (size_t)(((c2 >> 5) & 1) * 512 + ((c2 >> 3) & 3) * 128 + (r2 & 15) * 8 + (c2 & 7));
        float nv = bf2f(A_sw[na]);
        out[(size_t)r2 * D + c2] = nv + gate * att;
      }
    }
  }
}

// ---------------- K6 (fallback): f32-staging GEMM ----------------
#define BM 128
#define BN 128
#define BKf 32
#define LDK (BKf + 8)

__global__ __launch_bounds__(256) void k_gemm_f32(
    const float* __restrict__ no, const float* __restrict__ Wg,
    const float* __restrict__ bg, const float* __restrict__ attn,
    const float* __restrict__ vb, const float* __restrict__ VW,
    float* __restrict__ out) {
  __shared__ unsigned short As[BM * LDK];
  __shared__ unsigned short Bs[BN * LDK];
  __shared__ float ep[2048];

  int tid = threadIdx.x;
  int lane = tid & 63, wid = tid >> 6;
  int brow = blockIdx.x * BM;
  int bcol = blockIdx.y * BN;
  int wr = wid >> 1, wc = wid & 1;

  f32x4 acc[4][4];
#pragma unroll
  for (int m = 0; m < 4; ++m)
#pragma unroll
    for (int n = 0; n < 4; ++n) acc[m][n] = (f32x4){0.f, 0.f, 0.f, 0.f};

  int fr = lane & 15, fg = lane >> 4;

  for (int kt = 0; kt < D / BKf; ++kt) {
    int k0 = kt * BKf;
#pragma unroll
    for (int i = 0; i < 4; ++i) {
      int fid = tid + i * 256;
      int row = fid >> 3, c4 = (fid & 7) * 4;
      f32x4 a4 = *(const f32x4*)(no + (size_t)(brow + row) * D + k0 + c4);
      f32x4 b4 = *(const f32x4*)(Wg + (size_t)(bcol + row) * (2 * D) + k0 + c4);
      u16x4 ab, bb;
      ab[0] = f2bf(a4[0]); ab[1] = f2bf(a4[1]); ab[2] = f2bf(a4[2]); ab[3] = f2bf(a4[3]);
      bb[0] = f2bf(b4[0]); bb[1] = f2bf(b4[1]); bb[2] = f2bf(b4[2]); bb[3] = f2bf(b4[3]);
      *(u16x4*)(&As[row * LDK + c4]) = ab;
      *(u16x4*)(&Bs[row * LDK + c4]) = bb;
    }
    __syncthreads();
    s16x8 af[4], bfr[4];
#pragma unroll
    for (int m = 0; m < 4; ++m) af[m] = *(const s16x8*)(&As[(wr*64 + m*16 + fr) * LDK + fg*8]);
#pragma unroll
    for (int n = 0; n < 4; ++n) bfr[n] = *(const s16x8*)(&Bs[(wc*64 + n*16 + fr) * LDK + fg*8]);
#pragma unroll
    for (int m = 0; m < 4; ++m)
#pragma unroll
      for (int n = 0; n < 4; ++n)
        acc[m][n] = __builtin_amdgcn_mfma_f32_16x16x32_bf16(af[m], bfr[n], acc[m][n], 0, 0, 0);
    __syncthreads();
  }

  for (int x = tid; x < 640; x += 256) ep[x] = attn[(size_t)brow * TOPK + x];
  for (int x = tid; x < 640; x += 256) { int j = x >> 7, c = x & 127; ep[640 + x]  = VW[j*D + bcol + c]; }
  for (int x = tid; x < 640; x += 256) { int j = x >> 7, c = x & 127; ep[1280 + x] = vb[j*D + bcol + c]; }
  if (tid < 128) ep[1920 + tid] = bg[bcol + tid];
  __syncthreads();

#pragma unroll
  for (int m = 0; m < 4; ++m) {
    int rbase = wr * 64 + m * 16 + fg * 4;
#pragma unroll
    for (int n = 0; n < 4; ++n) {
      int c = wc * 64 + n * 16 + fr;
      float vw0 = ep[640 + 0*128 + c], vw1 = ep[640 + 1*128 + c], vw2 = ep[640 + 2*128 + c],
            vw3 = ep[640 + 3*128 + c], vw4 = ep[640 + 4*128 + c];
      float v0 = ep[1280 + 0*128 + c], v1 = ep[1280 + 1*128 + c], v2 = ep[1280 + 2*128 + c],
            v3 = ep[1280 + 3*128 + c], v4 = ep[1280 + 4*128 + c];
      float bgc = ep[1920 + c];
#pragma unroll
      for (int i = 0; i < 4; ++i) {
        int r = rbase + i;
        float a0 = ep[r*5+0], a1 = ep[r*5+1], a2 = ep[r*5+2], a3 = ep[r*5+3], a4 = ep[r*5+4];
        float gl = acc[m][n][i] + bgc + a0*vw0 + a1*vw1 + a2*vw2 + a3*vw3 + a4*vw4;
        float att = a0*v0 + a1*v1 + a2*v2 + a3*v3 + a4*v4;
        float gate = 1.0f / (1.0f + __expf(-gl));
        size_t gi = (size_t)(brow + r) * D + bcol + c;
        out[gi] = no[gi] + gate * att;
      }
    }
  }
}

extern "C" void kernel_launch(void* const* d_in, const int* in_sizes, int n_in,
                              void* d_out, int out_size, void* d_ws, size_t ws_size,
                              hipStream_t stream) {
  (void)in_sizes; (void)n_in; (void)out_size;
  const float* no    = (const float*)d_in[0];
  const float* ce    = (const float*)d_in[1];
  const float* bank  = (const float*)d_in[2];
  const float* mvals = (const float*)d_in[3];
  const float* Wq    = (const float*)d_in[4];
  const float* bq    = (const float*)d_in[5];
  const float* Wk    = (const float*)d_in[6];
  const float* bk    = (const float*)d_in[7];
  const float* Wv    = (const float*)d_in[8];
  const float* bvp   = (const float*)d_in[9];
  const float* Wg    = (const float*)d_in[10];
  const float* bg    = (const float*)d_in[11];
  float* out = (float*)d_out;

  char* ws = (char*)d_ws;
  float* sims     = (float*)(ws + 16384);
  float* top_sims = (float*)(ws + 220160);
  int*   top_idx  = (int*)  (ws + 220192);
  float* sbias    = (float*)(ws + 220224);
  float* kb       = (float*)(ws + 221184);
  float* vb       = (float*)(ws + 262144);
  float* VW       = (float*)(ws + 303104);
  float* KQpart   = (float*)(ws + 344064);
  float* attn     = (float*)(ws + 1695744);
  unsigned short* A_sw = (unsigned short*)(ws + 4194304);
  unsigned short* B_sw = (unsigned short*)(ws + 4194304 + (size_t)B_ROWS * D * 2);

  const size_t ws_need = 4194304 + (size_t)B_ROWS * D * 2 + (size_t)D * D * 2;
  const bool fast = ws_size >= ws_need;

  k_sims<<<2048, 256, 0, stream>>>(bank, ce, sims);
  k_topk<<<1, 1024, 0, stream>>>(sims, top_sims, top_idx);
  k_kv<<<512, 256, 0, stream>>>(mvals, top_idx, Wk, bk, Wv, bvp, kb, vb);
  k_prep<<<fast ? 801 : 769, 256, 0, stream>>>(Wq, bq, Wg, kb, vb, KQpart, VW, sbias, B_sw);
  if (fast) {
    k_attn<true><<<512, 512, 0, stream>>>(no, KQpart, sbias, top_sims, attn, A_sw);
    k_gemm_bf<<<512, 512, 0, stream>>>(A_sw, B_sw, bg, attn, vb, VW, out);
  } else {
    k_attn<false><<<512, 512, 0, stream>>>(no, KQpart, sbias, top_sims, attn, A_sw);
    k_gemm_f32<<<dim3(B_ROWS / BM, D / BN), 256, 0, stream>>>(no, Wg, bg, attn, vb, VW, out);
  }
}

// Round 13
// 460.969 us; speedup vs baseline: 1.4360x; 1.0961x over previous
//
#include <hip/hip_runtime.h>
#include <hip/hip_bf16.h>
#include <math.h>

#define D 2048
#define M_ROWS 50000
#define B_ROWS 16384
#define TOPK 5
#define EPSN 1e-12f

typedef __attribute__((ext_vector_type(4))) float f32x4;
typedef __attribute__((ext_vector_type(8))) short s16x8;
typedef __attribute__((ext_vector_type(4))) unsigned short u16x4;

__device__ __forceinline__ unsigned short f2bf(float f) {
  union { float f; unsigned int u; } x; x.f = f;
  unsigned int u = x.u;
  unsigned int r = u + 0x7fffu + ((u >> 16) & 1u);
  return (unsigned short)(r >> 16);
}

__device__ __forceinline__ float bf2f(unsigned short b) {
  union { unsigned int u; float f; } x; x.u = ((unsigned int)b) << 16;
  return x.f;
}

__device__ __forceinline__ void gload16(const void* g, void* l) {
  __builtin_amdgcn_global_load_lds(
      (const __attribute__((address_space(1))) unsigned int*)g,
      (__attribute__((address_space(3))) unsigned int*)l, 16, 0, 0);
}

// Subtiled bf16 layout for A_sw/B_sw, per 16-row x 64-K block (2048 elems):
//   addr(row,k) = (row>>4)*32768 + (k>>6)*1024 + ((k>>5)&1)*512 + ((k>>3)&3)*128 + (row&15)*8 + (k&7)
// Wave-contiguous 1KB segments; zero bank conflicts; global_load_lds linear-dest OK.

// ---------------- K1: sims + per-block top-5 candidates (qnorm fused) ----------------
// Each wave's lane 0 maintains a running top-5 of its rows; block merges 4 waves' top-5
// to one 5-candidate list. Global top-5 over (value desc, index asc) survives the local
// filter, so k_topk only reduces 2048*5 candidates. sims array eliminated.
__global__ void k_sims(const float* __restrict__ bank, const float* __restrict__ ce,
                       float* __restrict__ bval, int* __restrict__ bidx) {
  __shared__ float qs[D];
  __shared__ float red[256];
  __shared__ float wv_[4][TOPK];
  __shared__ int   wi_[4][TOPK];
  int tid = threadIdx.x;
  float s = 0.f;
  for (int t = tid; t < D; t += 256) { float x = ce[t]; s += x * x; }
  red[tid] = s; __syncthreads();
  for (int w = 128; w > 0; w >>= 1) { if (tid < w) red[tid] += red[tid + w]; __syncthreads(); }
  float qinv = 1.0f / fmaxf(sqrtf(red[0]), EPSN);
  for (int t = tid; t < D; t += 256) qs[t] = ce[t] * qinv;
  __syncthreads();
  int lane = tid & 63, wid = tid >> 6;
  int gw = (blockIdx.x << 2) + wid;
  int nw = gridDim.x << 2;
  float lv[TOPK]; int li[TOPK];
#pragma unroll
  for (int j = 0; j < TOPK; ++j) { lv[j] = -INFINITY; li[j] = 0x7fffffff; }
  for (int m = gw; m < M_ROWS; m += nw) {
    const float* row = bank + (size_t)m * D;
    float dot = 0.f, sq = 0.f;
#pragma unroll
    for (int i = 0; i < 8; ++i) {
      int off = i * 256 + lane * 4;
      f32x4 a = *(const f32x4*)(row + off);
      f32x4 q = *(const f32x4*)(qs + off);
      dot += a[0]*q[0] + a[1]*q[1] + a[2]*q[2] + a[3]*q[3];
      sq  += a[0]*a[0] + a[1]*a[1] + a[2]*a[2] + a[3]*a[3];
    }
    for (int off = 32; off; off >>= 1) {
      dot += __shfl_xor(dot, off, 64);
      sq  += __shfl_xor(sq,  off, 64);
    }
    if (lane == 0) {
      float v = dot / fmaxf(sqrtf(sq), EPSN);
      if (v > lv[TOPK-1] || (v == lv[TOPK-1] && m < li[TOPK-1])) {
        lv[TOPK-1] = v; li[TOPK-1] = m;
#pragma unroll
        for (int j = TOPK-1; j > 0; --j) {
          bool sw = (lv[j] > lv[j-1]) || (lv[j] == lv[j-1] && li[j] < li[j-1]);
          if (sw) { float tv=lv[j]; lv[j]=lv[j-1]; lv[j-1]=tv; int ti=li[j]; li[j]=li[j-1]; li[j-1]=ti; }
        }
      }
    }
  }
  if (lane == 0) {
#pragma unroll
    for (int j = 0; j < TOPK; ++j) { wv_[wid][j] = lv[j]; wi_[wid][j] = li[j]; }
  }
  __syncthreads();
  if (tid == 0) {
    float bv[TOPK]; int bi[TOPK];
    for (int j = 0; j < TOPK; ++j) { bv[j] = -INFINITY; bi[j] = 0x7fffffff; }
    for (int c = 0; c < 4 * TOPK; ++c) {
      float v = wv_[c / TOPK][c % TOPK]; int i = wi_[c / TOPK][c % TOPK];
      if (v > bv[TOPK-1] || (v == bv[TOPK-1] && i < bi[TOPK-1])) {
        bv[TOPK-1] = v; bi[TOPK-1] = i;
        for (int j = TOPK-1; j > 0; --j) {
          bool sw = (bv[j] > bv[j-1]) || (bv[j] == bv[j-1] && bi[j] < bi[j-1]);
          if (sw) { float tv=bv[j]; bv[j]=bv[j-1]; bv[j-1]=tv; int ti=bi[j]; bi[j]=bi[j-1]; bi[j-1]=ti; }
        }
      }
    }
    for (int j = 0; j < TOPK; ++j) { bval[blockIdx.x * TOPK + j] = bv[j]; bidx[blockIdx.x * TOPK + j] = bi[j]; }
  }
}

// ---------------- K2: top-5 over 2048*5 candidates ----------------
__global__ __launch_bounds__(1024) void k_topk(
    const float* __restrict__ bval, const int* __restrict__ bidx,
    float* __restrict__ top_sims, int* __restrict__ top_idx) {
  __shared__ float sval[1024 * TOPK];
  __shared__ int   sidx[1024 * TOPK];
  __shared__ float sv2[64 * TOPK];
  __shared__ int   si2[64 * TOPK];
  int tid = threadIdx.x;
  float lv[TOPK]; int li[TOPK];
#pragma unroll
  for (int j = 0; j < TOPK; ++j) { lv[j] = -INFINITY; li[j] = 0x7fffffff; }
  for (int m = tid; m < 2048 * TOPK; m += 1024) {
    float v = bval[m]; int idx = bidx[m];
    if (v > lv[TOPK-1] || (v == lv[TOPK-1] && idx < li[TOPK-1])) {
      lv[TOPK-1] = v; li[TOPK-1] = idx;
#pragma unroll
      for (int j = TOPK-1; j > 0; --j) {
        bool sw = (lv[j] > lv[j-1]) || (lv[j] == lv[j-1] && li[j] < li[j-1]);
        if (sw) { float tv=lv[j]; lv[j]=lv[j-1]; lv[j-1]=tv; int ti=li[j]; li[j]=li[j-1]; li[j-1]=ti; }
      }
    }
  }
#pragma unroll
  for (int j = 0; j < TOPK; ++j) { sval[tid*TOPK+j] = lv[j]; sidx[tid*TOPK+j] = li[j]; }
  __syncthreads();
  if (tid < 64) {
    float bv[TOPK]; int bi[TOPK];
    for (int j = 0; j < TOPK; ++j) { bv[j] = -INFINITY; bi[j] = 0x7fffffff; }
    for (int c = tid * 80; c < tid * 80 + 80; ++c) {
      float v = sval[c]; int i = sidx[c];
      if (v > bv[TOPK-1] || (v == bv[TOPK-1] && i < bi[TOPK-1])) {
        bv[TOPK-1] = v; bi[TOPK-1] = i;
        for (int j = TOPK-1; j > 0; --j) {
          bool sw = (bv[j] > bv[j-1]) || (bv[j] == bv[j-1] && bi[j] < bi[j-1]);
          if (sw) { float tv=bv[j]; bv[j]=bv[j-1]; bv[j-1]=tv; int ti=bi[j]; bi[j]=bi[j-1]; bi[j-1]=ti; }
        }
      }
    }
    for (int j = 0; j < TOPK; ++j) { sv2[tid*TOPK+j] = bv[j]; si2[tid*TOPK+j] = bi[j]; }
  }
  __syncthreads();
  if (tid == 0) {
    float bvv[TOPK]; int bii[TOPK];
    for (int j = 0; j < TOPK; ++j) { bvv[j] = -INFINITY; bii[j] = 0x7fffffff; }
    for (int c = 0; c < 64 * TOPK; ++c) {
      float v = sv2[c]; int i = si2[c];
      if (v > bvv[TOPK-1] || (v == bvv[TOPK-1] && i < bii[TOPK-1])) {
        bvv[TOPK-1] = v; bii[TOPK-1] = i;
        for (int j = TOPK-1; j > 0; --j) {
          bool sw = (bvv[j] > bvv[j-1]) || (bvv[j] == bvv[j-1] && bii[j] < bii[j-1]);
          if (sw) { float tv=bvv[j]; bvv[j]=bvv[j-1]; bvv[j-1]=tv; int ti=bii[j]; bii[j]=bii[j-1]; bii[j-1]=ti; }
        }
      }
    }
    for (int j = 0; j < TOPK; ++j) { top_sims[j] = bvv[j]; top_idx[j] = bii[j]; }
  }
}

// ---------------- K3: k,v = memories @ Wk/Wv^T + b ----------------
__global__ void k_kv(const float* __restrict__ mvals, const int* __restrict__ top_idx,
                     const float* __restrict__ Wk, const float* __restrict__ bk,
                     const float* __restrict__ Wv, const float* __restrict__ bvp,
                     float* __restrict__ kb, float* __restrict__ vb) {
  __shared__ float mem[TOPK][D];
  int tid = threadIdx.x;
  for (int j = 0; j < TOPK; ++j) {
    const float* src = mvals + (size_t)top_idx[j] * D;
    for (int t = tid; t < D; t += 256) mem[j][t] = src[t];
  }
  __syncthreads();
  int lane = tid & 63, wid = tid >> 6;
  int c = blockIdx.x * 4 + wid;
  const float* wkr = Wk + (size_t)c * D;
  const float* wvr = Wv + (size_t)c * D;
  float ak[TOPK] = {0,0,0,0,0}, av[TOPK] = {0,0,0,0,0};
#pragma unroll 2
  for (int i = 0; i < 8; ++i) {
    int off = i * 256 + lane * 4;
    f32x4 wk4 = *(const f32x4*)(wkr + off);
    f32x4 wv4 = *(const f32x4*)(wvr + off);
#pragma unroll
    for (int j = 0; j < TOPK; ++j) {
      f32x4 mv = *(const f32x4*)(&mem[j][off]);
      ak[j] += mv[0]*wk4[0] + mv[1]*wk4[1] + mv[2]*wk4[2] + mv[3]*wk4[3];
      av[j] += mv[0]*wv4[0] + mv[1]*wv4[1] + mv[2]*wv4[2] + mv[3]*wv4[3];
    }
  }
  for (int off = 32; off; off >>= 1) {
#pragma unroll
    for (int j = 0; j < TOPK; ++j) {
      ak[j] += __shfl_xor(ak[j], off, 64);
      av[j] += __shfl_xor(av[j], off, 64);
    }
  }
  if (lane == 0) {
#pragma unroll
    for (int j = 0; j < TOPK; ++j) { kb[j*D + c] = ak[j] + bk[c]; vb[j*D + c] = av[j] + bvp[c]; }
  }
}

// ---------------- K4: prep — KQ partials, VW, sbias, WgA bf16 cast (wave-coalesced) ----
__global__ void k_prep(const float* __restrict__ Wq, const float* __restrict__ bq,
                       const float* __restrict__ Wg,
                       const float* __restrict__ kb, const float* __restrict__ vb,
                       float* __restrict__ KQpart, float* __restrict__ VW,
                       float* __restrict__ sbias, unsigned short* __restrict__ B_sw) {
  __shared__ float sh[TOPK * D];
  int tid = threadIdx.x;
  int bid = blockIdx.x;
  if (bid < 256) {
    int cc = bid >> 3, tc = bid & 7;
    for (int x = tid; x < TOPK * 64; x += 256) sh[x] = kb[(x >> 6) * D + cc * 64 + (x & 63)];
    __syncthreads();
    float acc[TOPK] = {0,0,0,0,0};
    const float* wq = Wq + (size_t)(cc * 64) * D + tc * 256 + tid;
#pragma unroll 4
    for (int c = 0; c < 64; ++c) {
      float w = wq[(size_t)c * D];
#pragma unroll
      for (int j = 0; j < TOPK; ++j) acc[j] += sh[j * 64 + c] * w;
    }
#pragma unroll
    for (int j = 0; j < TOPK; ++j)
      KQpart[(size_t)(cc * TOPK + j) * D + tc * 256 + tid] = acc[j];
  } else if (bid < 768) {
    for (int x = tid; x < TOPK * D; x += 256) sh[x] = vb[x];
    __syncthreads();
    int lane = tid & 63, wid = tid >> 6;
    int c = (bid - 256) * 4 + wid;
    const float* wg = Wg + (size_t)c * (2 * D) + D;
    float acc[TOPK] = {0,0,0,0,0};
#pragma unroll 2
    for (int i = 0; i < 8; ++i) {
      int off = i * 256 + lane * 4;
      f32x4 g4 = *(const f32x4*)(wg + off);
#pragma unroll
      for (int j = 0; j < TOPK; ++j) {
        f32x4 vv = *(const f32x4*)(&sh[j*D + off]);
        acc[j] += vv[0]*g4[0] + vv[1]*g4[1] + vv[2]*g4[2] + vv[3]*g4[3];
      }
    }
    for (int off = 32; off; off >>= 1)
#pragma unroll
      for (int j = 0; j < TOPK; ++j) acc[j] += __shfl_xor(acc[j], off, 64);
    if (lane == 0)
      for (int j = 0; j < TOPK; ++j) VW[j*D + c] = acc[j];
  } else if (bid == 768) {
    for (int j = 0; j < TOPK; ++j) {
      float s = 0.f;
      for (int t = tid; t < D; t += 256) s += bq[t] * kb[j*D + t];
      sh[tid] = s; __syncthreads();
      for (int w = 128; w > 0; w >>= 1) { if (tid < w) sh[tid] += sh[tid + w]; __syncthreads(); }
      if (tid == 0) sbias[j] = sh[0];
      __syncthreads();
    }
  } else {
    int lane = tid & 63, wid = tid >> 6;
    int r0 = ((bid - 769) * 4 + wid) * 16;
    int rl = lane & 15, kg = lane >> 4;
    const float* src = Wg + (size_t)(r0 + rl) * (2 * D);
    size_t wbase = ((size_t)(r0 >> 4)) << 15;
#pragma unroll 4
    for (int it = 0; it < 64; ++it) {
      int k = it * 32 + kg * 8;
      f32x4 a = *(const f32x4*)(src + k);
      f32x4 b = *(const f32x4*)(src + k + 4);
      s16x8 p;
      p[0]=(short)f2bf(a[0]); p[1]=(short)f2bf(a[1]); p[2]=(short)f2bf(a[2]); p[3]=(short)f2bf(a[3]);
      p[4]=(short)f2bf(b[0]); p[5]=(short)f2bf(b[1]); p[6]=(short)f2bf(b[2]); p[7]=(short)f2bf(b[3]);
      *(s16x8*)(B_sw + wbase + ((size_t)it << 9) + lane * 8) = p;
    }
  }
}

// ---------------- K4b: reduce 32 KQ partials -> KQ (once) ----------------
__global__ void k_red(const float* __restrict__ KQpart, float* __restrict__ KQ) {
  int x = blockIdx.x * 256 + threadIdx.x;  // 40 blocks -> 10240
  float s = 0.f;
#pragma unroll 8
  for (int cc = 0; cc < 32; ++cc) s += KQpart[(size_t)cc * (TOPK * D) + x];
  KQ[x] = s;
}

// ---------------- K5: scores + softmax + fused no->bf16 cast (8-wave) ----------------
// 512 blocks x 512 threads; block = 32 rows = 2 rowgroups x 4 K-quarters (8 waves).
template <bool WRITE_CAST>
__global__ __launch_bounds__(512) void k_attn(
    const float* __restrict__ no, const float* __restrict__ KQ,
    const float* __restrict__ sbias, const float* __restrict__ top_sims,
    float* __restrict__ attn, unsigned short* __restrict__ A_sw) {
  __shared__ float kq[TOPK * D];
  __shared__ float red[8][16][TOPK + 1];
  int tid = threadIdx.x;
  for (int x = tid; x < TOPK * D; x += 512) kq[x] = KQ[x];
  __syncthreads();
  int lane = tid & 63, wid = tid >> 6;
  int g = wid >> 2, q = wid & 3;
  int b0 = blockIdx.x * 32;
  int rl = lane & 15, kg = lane >> 4;
  int rowi = b0 + g * 16 + rl;
  const float* row = no + (size_t)rowi * D;
  size_t wbase = ((size_t)((b0 >> 4) + g)) << 15;
  float acc[TOPK] = {0, 0, 0, 0, 0};
#pragma unroll 4
  for (int it = q * 16; it < q * 16 + 16; ++it) {
    int k = it * 32 + kg * 8;
    f32x4 a = __builtin_nontemporal_load((const f32x4*)(row + k));
    f32x4 b = __builtin_nontemporal_load((const f32x4*)(row + k + 4));
#pragma unroll
    for (int j = 0; j < TOPK; ++j) {
      f32x4 ka = *(const f32x4*)(&kq[j * D + k]);
      f32x4 kb2 = *(const f32x4*)(&kq[j * D + k + 4]);
      acc[j] += a[0]*ka[0] + a[1]*ka[1] + a[2]*ka[2] + a[3]*ka[3]
              + b[0]*kb2[0] + b[1]*kb2[1] + b[2]*kb2[2] + b[3]*kb2[3];
    }
    if (WRITE_CAST) {
      s16x8 p;
      p[0]=(short)f2bf(a[0]); p[1]=(short)f2bf(a[1]); p[2]=(short)f2bf(a[2]); p[3]=(short)f2bf(a[3]);
      p[4]=(short)f2bf(b[0]); p[5]=(short)f2bf(b[1]); p[6]=(short)f2bf(b[2]); p[7]=(short)f2bf(b[3]);
      *(s16x8*)(A_sw + wbase + ((size_t)it << 9) + lane * 8) = p;
    }
  }
#pragma unroll
  for (int j = 0; j < TOPK; ++j) {
    acc[j] += __shfl_xor(acc[j], 16, 64);
    acc[j] += __shfl_xor(acc[j], 32, 64);
  }
  if (lane < 16) {
#pragma unroll
    for (int j = 0; j < TOPK; ++j) red[wid][rl][j] = acc[j];
  }
  __syncthreads();
  if (q == 0 && lane < 16) {
    const float inv = 0.02209708691207961f;  // 1/sqrt(2048)
    float s[TOPK], mx = -INFINITY;
#pragma unroll
    for (int j = 0; j < TOPK; ++j) {
      float t = red[g*4+0][rl][j] + red[g*4+1][rl][j] + red[g*4+2][rl][j] + red[g*4+3][rl][j];
      s[j] = (t + sbias[j]) * inv * top_sims[j];
      mx = fmaxf(mx, s[j]);
    }
    float sum = 0.f;
#pragma unroll
    for (int j = 0; j < TOPK; ++j) { s[j] = __expf(s[j] - mx); sum += s[j]; }
    float r = 1.0f / sum;
#pragma unroll
    for (int j = 0; j < TOPK; ++j) attn[(size_t)rowi * TOPK + j] = s[j] * r;
  }
}

// ---------------- K6 (fast): 256x256, round-5 compiler-scheduled 2-phase dbuf --------
union GemmSmem {
  struct { unsigned short A[2][16384]; unsigned short B[2][16384]; } s;  // 128 KB
  float ep[4096];
};

__global__ __launch_bounds__(512, 1) void k_gemm_bf(
    const unsigned short* __restrict__ A_sw, const unsigned short* __restrict__ B_sw,
    const float* __restrict__ bg, const float* __restrict__ attn,
    const float* __restrict__ vb, const float* __restrict__ VW,
    float* __restrict__ out) {
  __shared__ GemmSmem sm;

  int tid = threadIdx.x;
  int lane = tid & 63, wid = tid >> 6;
  int fr = lane & 15, fg = lane >> 4;
  int wr = wid >> 2, wc = wid & 3;
  int rh0 = wid * 2, rh1 = wid * 2 + 1;

  int id = blockIdx.x;
  int mt = (id & 7) * 8 + (id >> 6);
  int nt = (id >> 3) & 7;
  int brow = mt * 256, bcol = nt * 256;
  int rbA = mt * 16, rbB = nt * 16;

  f32x4 acc[8][4];
#pragma unroll
  for (int m = 0; m < 8; ++m)
#pragma unroll
    for (int n = 0; n < 4; ++n) acc[m][n] = (f32x4){0.f, 0.f, 0.f, 0.f};

  const unsigned short* gA0 = A_sw + ((size_t)(rbA + rh0) << 15) + lane * 8;
  const unsigned short* gA1 = A_sw + ((size_t)(rbA + rh1) << 15) + lane * 8;
  const unsigned short* gB0 = B_sw + ((size_t)(rbB + rh0) << 15) + lane * 8;
  const unsigned short* gB1 = B_sw + ((size_t)(rbB + rh1) << 15) + lane * 8;

#define STG(b_) do {                                                      \
    gload16(gA0,       sm.s.A[b_] + rh0 * 1024);                          \
    gload16(gA0 + 512, sm.s.A[b_] + rh0 * 1024 + 512);                    \
    gload16(gA1,       sm.s.A[b_] + rh1 * 1024);                          \
    gload16(gA1 + 512, sm.s.A[b_] + rh1 * 1024 + 512);                    \
    gload16(gB0,       sm.s.B[b_] + rh0 * 1024);                          \
    gload16(gB0 + 512, sm.s.B[b_] + rh0 * 1024 + 512);                    \
    gload16(gB1,       sm.s.B[b_] + rh1 * 1024);                          \
    gload16(gB1 + 512, sm.s.B[b_] + rh1 * 1024 + 512);                    \
    gA0 += 1024; gA1 += 1024; gB0 += 1024; gB1 += 1024;                   \
  } while (0)

  STG(0);
  __syncthreads();

  int rdo = fg * 128 + fr * 8;
  for (int kt = 0; kt < 32; ++kt) {
    int b = kt & 1;
    if (kt < 31) STG(b ^ 1);
    const unsigned short* Ab = sm.s.A[b];
    const unsigned short* Bb = sm.s.B[b];
#pragma unroll
    for (int kk = 0; kk < 2; ++kk) {
      s16x8 af[8], bfr[4];
#pragma unroll
      for (int m = 0; m < 8; ++m) af[m]  = *(const s16x8*)(Ab + (wr*8 + m) * 1024 + kk * 512 + rdo);
#pragma unroll
      for (int n = 0; n < 4; ++n) bfr[n] = *(const s16x8*)(Bb + (wc*4 + n) * 1024 + kk * 512 + rdo);
#pragma unroll
      for (int n = 0; n < 4; ++n)
#pragma unroll
        for (int m = 0; m < 8; ++m)
          acc[m][n] = __builtin_amdgcn_mfma_f32_16x16x32_bf16(af[m], bfr[n], acc[m][n], 0, 0, 0);
    }
    __syncthreads();
  }

  for (int x = tid; x < 1280; x += 512) sm.ep[x] = attn[(size_t)brow * TOPK + x];
  for (int x = tid; x < 1280; x += 512) { int j = x >> 8, c = x & 255; sm.ep[1280 + x] = VW[j*D + bcol + c]; }
  for (int x = tid; x < 1280; x += 512) { int j = x >> 8, c = x & 255; sm.ep[2560 + x] = vb[j*D + bcol + c]; }
  if (tid < 256) sm.ep[3840 + tid] = bg[bcol + tid];
  __syncthreads();

#pragma unroll
  for (int m = 0; m < 8; ++m) {
    int rbase = wr * 128 + m * 16 + fg * 4;
#pragma unroll
    for (int n = 0; n < 4; ++n) {
      int c = wc * 64 + n * 16 + fr;
      float vw0 = sm.ep[1280 + 0*256 + c], vw1 = sm.ep[1280 + 1*256 + c], vw2 = sm.ep[1280 + 2*256 + c],
            vw3 = sm.ep[1280 + 3*256 + c], vw4 = sm.ep[1280 + 4*256 + c];
      float v0 = sm.ep[2560 + 0*256 + c], v1 = sm.ep[2560 + 1*256 + c], v2 = sm.ep[2560 + 2*256 + c],
            v3 = sm.ep[2560 + 3*256 + c], v4 = sm.ep[2560 + 4*256 + c];
      float bgc = sm.ep[3840 + c];
#pragma unroll
      for (int i = 0; i < 4; ++i) {
        int r = rbase + i;
        float a0 = sm.ep[r*5+0], a1 = sm.ep[r*5+1], a2 = sm.ep[r*5+2], a3 = sm.ep[r*5+3], a4 = sm.ep[r*5+4];
        float gl = acc[m][n][i] + bgc + a0*vw0 + a1*vw1 + a2*vw2 + a3*vw3 + a4*vw4;
        float att = a0*v0 + a1*v1 + a2*v2 + a3*v3 + a4*v4;
        float gate = 1.0f / (1.0f + __expf(-gl));
        int r2 = brow + r, c2 = bcol + c;
        size_t na = ((size_t)(r2 >> 4) << 15) + ((size_t)(c2 >> 6) << 10)
                  + (size_t)(((c2 >> 5) & 1) * 512 + ((c2 >> 3) & 3) * 128 + (r2 & 15) * 8 + (c2 & 7));
        float nv = bf2f(A_sw[na]);
        out[(size_t)r2 * D + c2] = nv + gate * att;
      }
    }
  }
}

// ---------------- K6 (fallback): f32-staging GEMM ----------------
#define BM 128
#define BN 128
#define BKf 32
#define LDK (BKf + 8)

__global__ __launch_bounds__(256) void k_gemm_f32(
    const float* __restrict__ no, const float* __restrict__ Wg,
    const float* __restrict__ bg, const float* __restrict__ attn,
    const float* __restrict__ vb, const float* __restrict__ VW,
    float* __restrict__ out) {
  __shared__ unsigned short As[BM * LDK];
  __shared__ unsigned short Bs[BN * LDK];
  __shared__ float ep[2048];

  int tid = threadIdx.x;
  int lane = tid & 63, wid = tid >> 6;
  int brow = blockIdx.x * BM;
  int bcol = blockIdx.y * BN;
  int wr = wid >> 1, wc = wid & 1;

  f32x4 acc[4][4];
#pragma unroll
  for (int m = 0; m < 4; ++m)
#pragma unroll
    for (int n = 0; n < 4; ++n) acc[m][n] = (f32x4){0.f, 0.f, 0.f, 0.f};

  int fr = lane & 15, fg = lane >> 4;

  for (int kt = 0; kt < D / BKf; ++kt) {
    int k0 = kt * BKf;
#pragma unroll
    for (int i = 0; i < 4; ++i) {
      int fid = tid + i * 256;
      int row = fid >> 3, c4 = (fid & 7) * 4;
      f32x4 a4 = *(const f32x4*)(no + (size_t)(brow + row) * D + k0 + c4);
      f32x4 b4 = *(const f32x4*)(Wg + (size_t)(bcol + row) * (2 * D) + k0 + c4);
      u16x4 ab, bb;
      ab[0] = f2bf(a4[0]); ab[1] = f2bf(a4[1]); ab[2] = f2bf(a4[2]); ab[3] = f2bf(a4[3]);
      bb[0] = f2bf(b4[0]); bb[1] = f2bf(b4[1]); bb[2] = f2bf(b4[2]); bb[3] = f2bf(b4[3]);
      *(u16x4*)(&As[row * LDK + c4]) = ab;
      *(u16x4*)(&Bs[row * LDK + c4]) = bb;
    }
    __syncthreads();
    s16x8 af[4], bfr[4];
#pragma unroll
    for (int m = 0; m < 4; ++m) af[m] = *(const s16x8*)(&As[(wr*64 + m*16 + fr) * LDK + fg*8]);
#pragma unroll
    for (int n = 0; n < 4; ++n) bfr[n] = *(const s16x8*)(&Bs[(wc*64 + n*16 + fr) * LDK + fg*8]);
#pragma unroll
    for (int m = 0; m < 4; ++m)
#pragma unroll
      for (int n = 0; n < 4; ++n)
        acc[m][n] = __builtin_amdgcn_mfma_f32_16x16x32_bf16(af[m], bfr[n], acc[m][n], 0, 0, 0);
    __syncthreads();
  }

  for (int x = tid; x < 640; x += 256) ep[x] = attn[(size_t)brow * TOPK + x];
  for (int x = tid; x < 640; x += 256) { int j = x >> 7, c = x & 127; ep[640 + x]  = VW[j*D + bcol + c]; }
  for (int x = tid; x < 640; x += 256) { int j = x >> 7, c = x & 127; ep[1280 + x] = vb[j*D + bcol + c]; }
  if (tid < 128) ep[1920 + tid] = bg[bcol + tid];
  __syncthreads();

#pragma unroll
  for (int m = 0; m < 4; ++m) {
    int rbase = wr * 64 + m * 16 + fg * 4;
#pragma unroll
    for (int n = 0; n < 4; ++n) {
      int c = wc * 64 + n * 16 + fr;
      float vw0 = ep[640 + 0*128 + c], vw1 = ep[640 + 1*128 + c], vw2 = ep[640 + 2*128 + c],
            vw3 = ep[640 + 3*128 + c], vw4 = ep[640 + 4*128 + c];
      float v0 = ep[1280 + 0*128 + c], v1 = ep[1280 + 1*128 + c], v2 = ep[1280 + 2*128 + c],
            v3 = ep[1280 + 3*128 + c], v4 = ep[1280 + 4*128 + c];
      float bgc = ep[1920 + c];
#pragma unroll
      for (int i = 0; i < 4; ++i) {
        int r = rbase + i;
        float a0 = ep[r*5+0], a1 = ep[r*5+1], a2 = ep[r*5+2], a3 = ep[r*5+3], a4 = ep[r*5+4];
        float gl = acc[m][n][i] + bgc + a0*vw0 + a1*vw1 + a2*vw2 + a3*vw3 + a4*vw4;
        float att = a0*v0 + a1*v1 + a2*v2 + a3*v3 + a4*v4;
        float gate = 1.0f / (1.0f + __expf(-gl));
        size_t gi = (size_t)(brow + r) * D + bcol + c;
        out[gi] = no[gi] + gate * att;
      }
    }
  }
}

extern "C" void kernel_launch(void* const* d_in, const int* in_sizes, int n_in,
                              void* d_out, int out_size, void* d_ws, size_t ws_size,
                              hipStream_t stream) {
  (void)in_sizes; (void)n_in; (void)out_size;
  const float* no    = (const float*)d_in[0];
  const float* ce    = (const float*)d_in[1];
  const float* bank  = (const float*)d_in[2];
  const float* mvals = (const float*)d_in[3];
  const float* Wq    = (const float*)d_in[4];
  const float* bq    = (const float*)d_in[5];
  const float* Wk    = (const float*)d_in[6];
  const float* bk    = (const float*)d_in[7];
  const float* Wv    = (const float*)d_in[8];
  const float* bvp   = (const float*)d_in[9];
  const float* Wg    = (const float*)d_in[10];
  const float* bg    = (const float*)d_in[11];
  float* out = (float*)d_out;

  char* ws = (char*)d_ws;
  float* top_sims = (float*)(ws + 220160);
  int*   top_idx  = (int*)  (ws + 220192);
  float* sbias    = (float*)(ws + 220224);
  float* kb       = (float*)(ws + 221184);
  float* vb       = (float*)(ws + 262144);
  float* VW       = (float*)(ws + 303104);
  float* KQpart   = (float*)(ws + 344064);   // 1.31 MB -> ends 1654784
  float* KQ       = (float*)(ws + 1654784);  // 40 KB -> ends 1695744
  float* attn     = (float*)(ws + 1695744);  // 327 KB -> ends 2023424
  float* bval     = (float*)(ws + 2023424);  // 2048*5 f = 40960
  int*   bidx     = (int*)  (ws + 2064384);  // 40960 -> ends 2105344
  unsigned short* A_sw = (unsigned short*)(ws + 4194304);
  unsigned short* B_sw = (unsigned short*)(ws + 4194304 + (size_t)B_ROWS * D * 2);

  const size_t ws_need = 4194304 + (size_t)B_ROWS * D * 2 + (size_t)D * D * 2;
  const bool fast = ws_size >= ws_need;

  k_sims<<<2048, 256, 0, stream>>>(bank, ce, bval, bidx);
  k_topk<<<1, 1024, 0, stream>>>(bval, bidx, top_sims, top_idx);
  k_kv<<<512, 256, 0, stream>>>(mvals, top_idx, Wk, bk, Wv, bvp, kb, vb);
  k_prep<<<fast ? 801 : 769, 256, 0, stream>>>(Wq, bq, Wg, kb, vb, KQpart, VW, sbias, B_sw);
  k_red<<<40, 256, 0, stream>>>(KQpart, KQ);
  if (fast) {
    k_attn<true><<<512, 512, 0, stream>>>(no, KQ, sbias, top_sims, attn, A_sw);
    k_gemm_bf<<<512, 512, 0, stream>>>(A_sw, B_sw, bg, attn, vb, VW, out);
  } else {
    k_attn<false><<<512, 512, 0, stream>>>(no, KQ, sbias, top_sims, attn, A_sw);
    k_gemm_f32<<<dim3(B_ROWS / BM, D / BN), 256, 0, stream>>>(no, Wg, bg, attn, vb, VW, out);
  }
}

// Round 14
// 460.874 us; speedup vs baseline: 1.4363x; 1.0002x over previous
//
#include <hip/hip_runtime.h>
#include <hip/hip_bf16.h>
#include <math.h>

#define D 2048
#define M_ROWS 50000
#define B_ROWS 16384
#define TOPK 5
#define EPSN 1e-12f

typedef __attribute__((ext_vector_type(4))) float f32x4;
typedef __attribute__((ext_vector_type(8))) short s16x8;
typedef __attribute__((ext_vector_type(4))) unsigned short u16x4;

__device__ __forceinline__ unsigned short f2bf(float f) {
  union { float f; unsigned int u; } x; x.f = f;
  unsigned int u = x.u;
  unsigned int r = u + 0x7fffu + ((u >> 16) & 1u);
  return (unsigned short)(r >> 16);
}

__device__ __forceinline__ float bf2f(unsigned short b) {
  union { unsigned int u; float f; } x; x.u = ((unsigned int)b) << 16;
  return x.f;
}

__device__ __forceinline__ void gload16(const void* g, void* l) {
  __builtin_amdgcn_global_load_lds(
      (const __attribute__((address_space(1))) unsigned int*)g,
      (__attribute__((address_space(3))) unsigned int*)l, 16, 0, 0);
}

// Subtiled bf16 layout for A_sw/B_sw, per 16-row x 64-K block (2048 elems):
//   addr(row,k) = (row>>4)*32768 + (k>>6)*1024 + ((k>>5)&1)*512 + ((k>>3)&3)*128 + (row&15)*8 + (k&7)
// Wave-contiguous 1KB segments; zero bank conflicts; global_load_lds linear-dest OK.

// ---------------- K1: sims + per-block top-5 candidates; castB rides along ----------
// Blocks [0,2048): cosine sims over the bank (fixed 8192-wave partition) + per-block
// top-5 candidate output. Blocks [2048,2080) (fast mode only): Wg->bf16 subtiled castB
// — depends only on Wg, so it overlaps the 410MB bank scan instead of sitting serially
// in k_prep on the dependency chain.
template <bool CASTB>
__global__ void k_sims(const float* __restrict__ bank, const float* __restrict__ ce,
                       float* __restrict__ bval, int* __restrict__ bidx,
                       const float* __restrict__ Wg, unsigned short* __restrict__ B_sw) {
  int tid = threadIdx.x;
  int lane = tid & 63, wid = tid >> 6;
  if (CASTB && blockIdx.x >= 2048) {
    int r0 = (((int)blockIdx.x - 2048) * 4 + wid) * 16;
    int rl = lane & 15, kg = lane >> 4;
    const float* src = Wg + (size_t)(r0 + rl) * (2 * D);
    size_t wbase = ((size_t)(r0 >> 4)) << 15;
#pragma unroll 4
    for (int it = 0; it < 64; ++it) {
      int k = it * 32 + kg * 8;
      f32x4 a = *(const f32x4*)(src + k);
      f32x4 b = *(const f32x4*)(src + k + 4);
      s16x8 p;
      p[0]=(short)f2bf(a[0]); p[1]=(short)f2bf(a[1]); p[2]=(short)f2bf(a[2]); p[3]=(short)f2bf(a[3]);
      p[4]=(short)f2bf(b[0]); p[5]=(short)f2bf(b[1]); p[6]=(short)f2bf(b[2]); p[7]=(short)f2bf(b[3]);
      *(s16x8*)(B_sw + wbase + ((size_t)it << 9) + lane * 8) = p;
    }
    return;
  }
  __shared__ float qs[D];
  __shared__ float red[256];
  __shared__ float wv_[4][TOPK];
  __shared__ int   wi_[4][TOPK];
  float s = 0.f;
  for (int t = tid; t < D; t += 256) { float x = ce[t]; s += x * x; }
  red[tid] = s; __syncthreads();
  for (int w = 128; w > 0; w >>= 1) { if (tid < w) red[tid] += red[tid + w]; __syncthreads(); }
  float qinv = 1.0f / fmaxf(sqrtf(red[0]), EPSN);
  for (int t = tid; t < D; t += 256) qs[t] = ce[t] * qinv;
  __syncthreads();
  int gw = ((int)blockIdx.x << 2) + wid;
  const int nw = 8192;  // fixed: 2048 sims blocks x 4 waves (castB blocks excluded)
  float lv[TOPK]; int li[TOPK];
#pragma unroll
  for (int j = 0; j < TOPK; ++j) { lv[j] = -INFINITY; li[j] = 0x7fffffff; }
  for (int m = gw; m < M_ROWS; m += nw) {
    const float* row = bank + (size_t)m * D;
    float dot = 0.f, sq = 0.f;
#pragma unroll
    for (int i = 0; i < 8; ++i) {
      int off = i * 256 + lane * 4;
      f32x4 a = *(const f32x4*)(row + off);
      f32x4 q = *(const f32x4*)(qs + off);
      dot += a[0]*q[0] + a[1]*q[1] + a[2]*q[2] + a[3]*q[3];
      sq  += a[0]*a[0] + a[1]*a[1] + a[2]*a[2] + a[3]*a[3];
    }
    for (int off = 32; off; off >>= 1) {
      dot += __shfl_xor(dot, off, 64);
      sq  += __shfl_xor(sq,  off, 64);
    }
    if (lane == 0) {
      float v = dot / fmaxf(sqrtf(sq), EPSN);
      if (v > lv[TOPK-1] || (v == lv[TOPK-1] && m < li[TOPK-1])) {
        lv[TOPK-1] = v; li[TOPK-1] = m;
#pragma unroll
        for (int j = TOPK-1; j > 0; --j) {
          bool sw = (lv[j] > lv[j-1]) || (lv[j] == lv[j-1] && li[j] < li[j-1]);
          if (sw) { float tv=lv[j]; lv[j]=lv[j-1]; lv[j-1]=tv; int ti=li[j]; li[j]=li[j-1]; li[j-1]=ti; }
        }
      }
    }
  }
  if (lane == 0) {
#pragma unroll
    for (int j = 0; j < TOPK; ++j) { wv_[wid][j] = lv[j]; wi_[wid][j] = li[j]; }
  }
  __syncthreads();
  if (tid == 0) {
    float bv[TOPK]; int bi[TOPK];
    for (int j = 0; j < TOPK; ++j) { bv[j] = -INFINITY; bi[j] = 0x7fffffff; }
    for (int c = 0; c < 4 * TOPK; ++c) {
      float v = wv_[c / TOPK][c % TOPK]; int i = wi_[c / TOPK][c % TOPK];
      if (v > bv[TOPK-1] || (v == bv[TOPK-1] && i < bi[TOPK-1])) {
        bv[TOPK-1] = v; bi[TOPK-1] = i;
        for (int j = TOPK-1; j > 0; --j) {
          bool sw = (bv[j] > bv[j-1]) || (bv[j] == bv[j-1] && bi[j] < bi[j-1]);
          if (sw) { float tv=bv[j]; bv[j]=bv[j-1]; bv[j-1]=tv; int ti=bi[j]; bi[j]=bi[j-1]; bi[j-1]=ti; }
        }
      }
    }
    for (int j = 0; j < TOPK; ++j) { bval[blockIdx.x * TOPK + j] = bv[j]; bidx[blockIdx.x * TOPK + j] = bi[j]; }
  }
}

// ---------------- K2: top-5 over 2048*5 candidates ----------------
__global__ __launch_bounds__(1024) void k_topk(
    const float* __restrict__ bval, const int* __restrict__ bidx,
    float* __restrict__ top_sims, int* __restrict__ top_idx) {
  __shared__ float sval[1024 * TOPK];
  __shared__ int   sidx[1024 * TOPK];
  __shared__ float sv2[64 * TOPK];
  __shared__ int   si2[64 * TOPK];
  int tid = threadIdx.x;
  float lv[TOPK]; int li[TOPK];
#pragma unroll
  for (int j = 0; j < TOPK; ++j) { lv[j] = -INFINITY; li[j] = 0x7fffffff; }
  for (int m = tid; m < 2048 * TOPK; m += 1024) {
    float v = bval[m]; int idx = bidx[m];
    if (v > lv[TOPK-1] || (v == lv[TOPK-1] && idx < li[TOPK-1])) {
      lv[TOPK-1] = v; li[TOPK-1] = idx;
#pragma unroll
      for (int j = TOPK-1; j > 0; --j) {
        bool sw = (lv[j] > lv[j-1]) || (lv[j] == lv[j-1] && li[j] < li[j-1]);
        if (sw) { float tv=lv[j]; lv[j]=lv[j-1]; lv[j-1]=tv; int ti=li[j]; li[j]=li[j-1]; li[j-1]=ti; }
      }
    }
  }
#pragma unroll
  for (int j = 0; j < TOPK; ++j) { sval[tid*TOPK+j] = lv[j]; sidx[tid*TOPK+j] = li[j]; }
  __syncthreads();
  if (tid < 64) {
    float bv[TOPK]; int bi[TOPK];
    for (int j = 0; j < TOPK; ++j) { bv[j] = -INFINITY; bi[j] = 0x7fffffff; }
    for (int c = tid * 80; c < tid * 80 + 80; ++c) {
      float v = sval[c]; int i = sidx[c];
      if (v > bv[TOPK-1] || (v == bv[TOPK-1] && i < bi[TOPK-1])) {
        bv[TOPK-1] = v; bi[TOPK-1] = i;
        for (int j = TOPK-1; j > 0; --j) {
          bool sw = (bv[j] > bv[j-1]) || (bv[j] == bv[j-1] && bi[j] < bi[j-1]);
          if (sw) { float tv=bv[j]; bv[j]=bv[j-1]; bv[j-1]=tv; int ti=bi[j]; bi[j]=bi[j-1]; bi[j-1]=ti; }
        }
      }
    }
    for (int j = 0; j < TOPK; ++j) { sv2[tid*TOPK+j] = bv[j]; si2[tid*TOPK+j] = bi[j]; }
  }
  __syncthreads();
  if (tid == 0) {
    float bvv[TOPK]; int bii[TOPK];
    for (int j = 0; j < TOPK; ++j) { bvv[j] = -INFINITY; bii[j] = 0x7fffffff; }
    for (int c = 0; c < 64 * TOPK; ++c) {
      float v = sv2[c]; int i = si2[c];
      if (v > bvv[TOPK-1] || (v == bvv[TOPK-1] && i < bii[TOPK-1])) {
        bvv[TOPK-1] = v; bii[TOPK-1] = i;
        for (int j = TOPK-1; j > 0; --j) {
          bool sw = (bvv[j] > bvv[j-1]) || (bvv[j] == bvv[j-1] && bii[j] < bii[j-1]);
          if (sw) { float tv=bvv[j]; bvv[j]=bvv[j-1]; bvv[j-1]=tv; int ti=bii[j]; bii[j]=bii[j-1]; bii[j-1]=ti; }
        }
      }
    }
    for (int j = 0; j < TOPK; ++j) { top_sims[j] = bvv[j]; top_idx[j] = bii[j]; }
  }
}

// ---------------- K3: k,v = memories @ Wk/Wv^T + b ----------------
__global__ void k_kv(const float* __restrict__ mvals, const int* __restrict__ top_idx,
                     const float* __restrict__ Wk, const float* __restrict__ bk,
                     const float* __restrict__ Wv, const float* __restrict__ bvp,
                     float* __restrict__ kb, float* __restrict__ vb) {
  __shared__ float mem[TOPK][D];
  int tid = threadIdx.x;
  for (int j = 0; j < TOPK; ++j) {
    const float* src = mvals + (size_t)top_idx[j] * D;
    for (int t = tid; t < D; t += 256) mem[j][t] = src[t];
  }
  __syncthreads();
  int lane = tid & 63, wid = tid >> 6;
  int c = blockIdx.x * 4 + wid;
  const float* wkr = Wk + (size_t)c * D;
  const float* wvr = Wv + (size_t)c * D;
  float ak[TOPK] = {0,0,0,0,0}, av[TOPK] = {0,0,0,0,0};
#pragma unroll 2
  for (int i = 0; i < 8; ++i) {
    int off = i * 256 + lane * 4;
    f32x4 wk4 = *(const f32x4*)(wkr + off);
    f32x4 wv4 = *(const f32x4*)(wvr + off);
#pragma unroll
    for (int j = 0; j < TOPK; ++j) {
      f32x4 mv = *(const f32x4*)(&mem[j][off]);
      ak[j] += mv[0]*wk4[0] + mv[1]*wk4[1] + mv[2]*wk4[2] + mv[3]*wk4[3];
      av[j] += mv[0]*wv4[0] + mv[1]*wv4[1] + mv[2]*wv4[2] + mv[3]*wv4[3];
    }
  }
  for (int off = 32; off; off >>= 1) {
#pragma unroll
    for (int j = 0; j < TOPK; ++j) {
      ak[j] += __shfl_xor(ak[j], off, 64);
      av[j] += __shfl_xor(av[j], off, 64);
    }
  }
  if (lane == 0) {
#pragma unroll
    for (int j = 0; j < TOPK; ++j) { kb[j*D + c] = ak[j] + bk[c]; vb[j*D + c] = av[j] + bvp[c]; }
  }
}

// ---------------- K4: prep — KQ partials (256), VW (512), sbias (1) ----------------
__global__ void k_prep(const float* __restrict__ Wq, const float* __restrict__ bq,
                       const float* __restrict__ Wg,
                       const float* __restrict__ kb, const float* __restrict__ vb,
                       float* __restrict__ KQpart, float* __restrict__ VW,
                       float* __restrict__ sbias) {
  __shared__ float sh[TOPK * D];
  int tid = threadIdx.x;
  int bid = blockIdx.x;
  if (bid < 256) {
    int cc = bid >> 3, tc = bid & 7;
    for (int x = tid; x < TOPK * 64; x += 256) sh[x] = kb[(x >> 6) * D + cc * 64 + (x & 63)];
    __syncthreads();
    float acc[TOPK] = {0,0,0,0,0};
    const float* wq = Wq + (size_t)(cc * 64) * D + tc * 256 + tid;
#pragma unroll 4
    for (int c = 0; c < 64; ++c) {
      float w = wq[(size_t)c * D];
#pragma unroll
      for (int j = 0; j < TOPK; ++j) acc[j] += sh[j * 64 + c] * w;
    }
#pragma unroll
    for (int j = 0; j < TOPK; ++j)
      KQpart[(size_t)(cc * TOPK + j) * D + tc * 256 + tid] = acc[j];
  } else if (bid < 768) {
    for (int x = tid; x < TOPK * D; x += 256) sh[x] = vb[x];
    __syncthreads();
    int lane = tid & 63, wid = tid >> 6;
    int c = (bid - 256) * 4 + wid;
    const float* wg = Wg + (size_t)c * (2 * D) + D;
    float acc[TOPK] = {0,0,0,0,0};
#pragma unroll 2
    for (int i = 0; i < 8; ++i) {
      int off = i * 256 + lane * 4;
      f32x4 g4 = *(const f32x4*)(wg + off);
#pragma unroll
      for (int j = 0; j < TOPK; ++j) {
        f32x4 vv = *(const f32x4*)(&sh[j*D + off]);
        acc[j] += vv[0]*g4[0] + vv[1]*g4[1] + vv[2]*g4[2] + vv[3]*g4[3];
      }
    }
    for (int off = 32; off; off >>= 1)
#pragma unroll
      for (int j = 0; j < TOPK; ++j) acc[j] += __shfl_xor(acc[j], off, 64);
    if (lane == 0)
      for (int j = 0; j < TOPK; ++j) VW[j*D + c] = acc[j];
  } else {
    for (int j = 0; j < TOPK; ++j) {
      float s = 0.f;
      for (int t = tid; t < D; t += 256) s += bq[t] * kb[j*D + t];
      sh[tid] = s; __syncthreads();
      for (int w = 128; w > 0; w >>= 1) { if (tid < w) sh[tid] += sh[tid + w]; __syncthreads(); }
      if (tid == 0) sbias[j] = sh[0];
      __syncthreads();
    }
  }
}

// ---------------- K4b: reduce 32 KQ partials -> KQ (once) ----------------
__global__ void k_red(const float* __restrict__ KQpart, float* __restrict__ KQ) {
  int x = blockIdx.x * 256 + threadIdx.x;  // 40 blocks -> 10240
  float s = 0.f;
#pragma unroll 8
  for (int cc = 0; cc < 32; ++cc) s += KQpart[(size_t)cc * (TOPK * D) + x];
  KQ[x] = s;
}

// ---------------- K5: scores + softmax + fused no->bf16 cast (8-wave) ----------------
template <bool WRITE_CAST>
__global__ __launch_bounds__(512) void k_attn(
    const float* __restrict__ no, const float* __restrict__ KQ,
    const float* __restrict__ sbias, const float* __restrict__ top_sims,
    float* __restrict__ attn, unsigned short* __restrict__ A_sw) {
  __shared__ float kq[TOPK * D];
  __shared__ float red[8][16][TOPK + 1];
  int tid = threadIdx.x;
  for (int x = tid; x < TOPK * D; x += 512) kq[x] = KQ[x];
  __syncthreads();
  int lane = tid & 63, wid = tid >> 6;
  int g = wid >> 2, q = wid & 3;
  int b0 = blockIdx.x * 32;
  int rl = lane & 15, kg = lane >> 4;
  int rowi = b0 + g * 16 + rl;
  const float* row = no + (size_t)rowi * D;
  size_t wbase = ((size_t)((b0 >> 4) + g)) << 15;
  float acc[TOPK] = {0, 0, 0, 0, 0};
#pragma unroll 4
  for (int it = q * 16; it < q * 16 + 16; ++it) {
    int k = it * 32 + kg * 8;
    f32x4 a = __builtin_nontemporal_load((const f32x4*)(row + k));
    f32x4 b = __builtin_nontemporal_load((const f32x4*)(row + k + 4));
#pragma unroll
    for (int j = 0; j < TOPK; ++j) {
      f32x4 ka = *(const f32x4*)(&kq[j * D + k]);
      f32x4 kb2 = *(const f32x4*)(&kq[j * D + k + 4]);
      acc[j] += a[0]*ka[0] + a[1]*ka[1] + a[2]*ka[2] + a[3]*ka[3]
              + b[0]*kb2[0] + b[1]*kb2[1] + b[2]*kb2[2] + b[3]*kb2[3];
    }
    if (WRITE_CAST) {
      s16x8 p;
      p[0]=(short)f2bf(a[0]); p[1]=(short)f2bf(a[1]); p[2]=(short)f2bf(a[2]); p[3]=(short)f2bf(a[3]);
      p[4]=(short)f2bf(b[0]); p[5]=(short)f2bf(b[1]); p[6]=(short)f2bf(b[2]); p[7]=(short)f2bf(b[3]);
      *(s16x8*)(A_sw + wbase + ((size_t)it << 9) + lane * 8) = p;
    }
  }
#pragma unroll
  for (int j = 0; j < TOPK; ++j) {
    acc[j] += __shfl_xor(acc[j], 16, 64);
    acc[j] += __shfl_xor(acc[j], 32, 64);
  }
  if (lane < 16) {
#pragma unroll
    for (int j = 0; j < TOPK; ++j) red[wid][rl][j] = acc[j];
  }
  __syncthreads();
  if (q == 0 && lane < 16) {
    const float inv = 0.02209708691207961f;  // 1/sqrt(2048)
    float s[TOPK], mx = -INFINITY;
#pragma unroll
    for (int j = 0; j < TOPK; ++j) {
      float t = red[g*4+0][rl][j] + red[g*4+1][rl][j] + red[g*4+2][rl][j] + red[g*4+3][rl][j];
      s[j] = (t + sbias[j]) * inv * top_sims[j];
      mx = fmaxf(mx, s[j]);
    }
    float sum = 0.f;
#pragma unroll
    for (int j = 0; j < TOPK; ++j) { s[j] = __expf(s[j] - mx); sum += s[j]; }
    float r = 1.0f / sum;
#pragma unroll
    for (int j = 0; j < TOPK; ++j) attn[(size_t)rowi * TOPK + j] = s[j] * r;
  }
}

// ---------------- K6 (fast): 256x256, compiler-scheduled 2-phase dbuf (plateau) -----
union GemmSmem {
  struct { unsigned short A[2][16384]; unsigned short B[2][16384]; } s;  // 128 KB
  float ep[4096];
};

__global__ __launch_bounds__(512, 1) void k_gemm_bf(
    const unsigned short* __restrict__ A_sw, const unsigned short* __restrict__ B_sw,
    const float* __restrict__ bg, const float* __restrict__ attn,
    const float* __restrict__ vb, const float* __restrict__ VW,
    float* __restrict__ out) {
  __shared__ GemmSmem sm;

  int tid = threadIdx.x;
  int lane = tid & 63, wid = tid >> 6;
  int fr = lane & 15, fg = lane >> 4;
  int wr = wid >> 2, wc = wid & 3;
  int rh0 = wid * 2, rh1 = wid * 2 + 1;

  int id = blockIdx.x;
  int mt = (id & 7) * 8 + (id >> 6);
  int nt = (id >> 3) & 7;
  int brow = mt * 256, bcol = nt * 256;
  int rbA = mt * 16, rbB = nt * 16;

  f32x4 acc[8][4];
#pragma unroll
  for (int m = 0; m < 8; ++m)
#pragma unroll
    for (int n = 0; n < 4; ++n) acc[m][n] = (f32x4){0.f, 0.f, 0.f, 0.f};

  const unsigned short* gA0 = A_sw + ((size_t)(rbA + rh0) << 15) + lane * 8;
  const unsigned short* gA1 = A_sw + ((size_t)(rbA + rh1) << 15) + lane * 8;
  const unsigned short* gB0 = B_sw + ((size_t)(rbB + rh0) << 15) + lane * 8;
  const unsigned short* gB1 = B_sw + ((size_t)(rbB + rh1) << 15) + lane * 8;

#define STG(b_) do {                                                      \
    gload16(gA0,       sm.s.A[b_] + rh0 * 1024);                          \
    gload16(gA0 + 512, sm.s.A[b_] + rh0 * 1024 + 512);                    \
    gload16(gA1,       sm.s.A[b_] + rh1 * 1024);                          \
    gload16(gA1 + 512, sm.s.A[b_] + rh1 * 1024 + 512);                    \
    gload16(gB0,       sm.s.B[b_] + rh0 * 1024);                          \
    gload16(gB0 + 512, sm.s.B[b_] + rh0 * 1024 + 512);                    \
    gload16(gB1,       sm.s.B[b_] + rh1 * 1024);                          \
    gload16(gB1 + 512, sm.s.B[b_] + rh1 * 1024 + 512);                    \
    gA0 += 1024; gA1 += 1024; gB0 += 1024; gB1 += 1024;                   \
  } while (0)

  STG(0);
  __syncthreads();

  int rdo = fg * 128 + fr * 8;
  for (int kt = 0; kt < 32; ++kt) {
    int b = kt & 1;
    if (kt < 31) STG(b ^ 1);
    const unsigned short* Ab = sm.s.A[b];
    const unsigned short* Bb = sm.s.B[b];
#pragma unroll
    for (int kk = 0; kk < 2; ++kk) {
      s16x8 af[8], bfr[4];
#pragma unroll
      for (int m = 0; m < 8; ++m) af[m]  = *(const s16x8*)(Ab + (wr*8 + m) * 1024 + kk * 512 + rdo);
#pragma unroll
      for (int n = 0; n < 4; ++n) bfr[n] = *(const s16x8*)(Bb + (wc*4 + n) * 1024 + kk * 512 + rdo);
#pragma unroll
      for (int n = 0; n < 4; ++n)
#pragma unroll
        for (int m = 0; m < 8; ++m)
          acc[m][n] = __builtin_amdgcn_mfma_f32_16x16x32_bf16(af[m], bfr[n], acc[m][n], 0, 0, 0);
    }
    __syncthreads();
  }

  for (int x = tid; x < 1280; x += 512) sm.ep[x] = attn[(size_t)brow * TOPK + x];
  for (int x = tid; x < 1280; x += 512) { int j = x >> 8, c = x & 255; sm.ep[1280 + x] = VW[j*D + bcol + c]; }
  for (int x = tid; x < 1280; x += 512) { int j = x >> 8, c = x & 255; sm.ep[2560 + x] = vb[j*D + bcol + c]; }
  if (tid < 256) sm.ep[3840 + tid] = bg[bcol + tid];
  __syncthreads();

#pragma unroll
  for (int m = 0; m < 8; ++m) {
    int rbase = wr * 128 + m * 16 + fg * 4;
#pragma unroll
    for (int n = 0; n < 4; ++n) {
      int c = wc * 64 + n * 16 + fr;
      float vw0 = sm.ep[1280 + 0*256 + c], vw1 = sm.ep[1280 + 1*256 + c], vw2 = sm.ep[1280 + 2*256 + c],
            vw3 = sm.ep[1280 + 3*256 + c], vw4 = sm.ep[1280 + 4*256 + c];
      float v0 = sm.ep[2560 + 0*256 + c], v1 = sm.ep[2560 + 1*256 + c], v2 = sm.ep[2560 + 2*256 + c],
            v3 = sm.ep[2560 + 3*256 + c], v4 = sm.ep[2560 + 4*256 + c];
      float bgc = sm.ep[3840 + c];
#pragma unroll
      for (int i = 0; i < 4; ++i) {
        int r = rbase + i;
        float a0 = sm.ep[r*5+0], a1 = sm.ep[r*5+1], a2 = sm.ep[r*5+2], a3 = sm.ep[r*5+3], a4 = sm.ep[r*5+4];
        float gl = acc[m][n][i] + bgc + a0*vw0 + a1*vw1 + a2*vw2 + a3*vw3 + a4*vw4;
        float att = a0*v0 + a1*v1 + a2*v2 + a3*v3 + a4*v4;
        float gate = 1.0f / (1.0f + __expf(-gl));
        int r2 = brow + r, c2 = bcol + c;
        size_t na = ((size_t)(r2 >> 4) << 15) + ((size_t)(c2 >> 6) << 10)
                  + (size_t)(((c2 >> 5) & 1) * 512 + ((c2 >> 3) & 3) * 128 + (r2 & 15) * 8 + (c2 & 7));
        float nv = bf2f(A_sw[na]);
        out[(size_t)r2 * D + c2] = nv + gate * att;
      }
    }
  }
}

// ---------------- K6 (fallback): f32-staging GEMM ----------------
#define BM 128
#define BN 128
#define BKf 32
#define LDK (BKf + 8)

__global__ __launch_bounds__(256) void k_gemm_f32(
    const float* __restrict__ no, const float* __restrict__ Wg,
    const float* __restrict__ bg, const float* __restrict__ attn,
    const float* __restrict__ vb, const float* __restrict__ VW,
    float* __restrict__ out) {
  __shared__ unsigned short As[BM * LDK];
  __shared__ unsigned short Bs[BN * LDK];
  __shared__ float ep[2048];

  int tid = threadIdx.x;
  int lane = tid & 63, wid = tid >> 6;
  int brow = blockIdx.x * BM;
  int bcol = blockIdx.y * BN;
  int wr = wid >> 1, wc = wid & 1;

  f32x4 acc[4][4];
#pragma unroll
  for (int m = 0; m < 4; ++m)
#pragma unroll
    for (int n = 0; n < 4; ++n) acc[m][n] = (f32x4){0.f, 0.f, 0.f, 0.f};

  int fr = lane & 15, fg = lane >> 4;

  for (int kt = 0; kt < D / BKf; ++kt) {
    int k0 = kt * BKf;
#pragma unroll
    for (int i = 0; i < 4; ++i) {
      int fid = tid + i * 256;
      int row = fid >> 3, c4 = (fid & 7) * 4;
      f32x4 a4 = *(const f32x4*)(no + (size_t)(brow + row) * D + k0 + c4);
      f32x4 b4 = *(const f32x4*)(Wg + (size_t)(bcol + row) * (2 * D) + k0 + c4);
      u16x4 ab, bb;
      ab[0] = f2bf(a4[0]); ab[1] = f2bf(a4[1]); ab[2] = f2bf(a4[2]); ab[3] = f2bf(a4[3]);
      bb[0] = f2bf(b4[0]); bb[1] = f2bf(b4[1]); bb[2] = f2bf(b4[2]); bb[3] = f2bf(b4[3]);
      *(u16x4*)(&As[row * LDK + c4]) = ab;
      *(u16x4*)(&Bs[row * LDK + c4]) = bb;
    }
    __syncthreads();
    s16x8 af[4], bfr[4];
#pragma unroll
    for (int m = 0; m < 4; ++m) af[m] = *(const s16x8*)(&As[(wr*64 + m*16 + fr) * LDK + fg*8]);
#pragma unroll
    for (int n = 0; n < 4; ++n) bfr[n] = *(const s16x8*)(&Bs[(wc*64 + n*16 + fr) * LDK + fg*8]);
#pragma unroll
    for (int m = 0; m < 4; ++m)
#pragma unroll
      for (int n = 0; n < 4; ++n)
        acc[m][n] = __builtin_amdgcn_mfma_f32_16x16x32_bf16(af[m], bfr[n], acc[m][n], 0, 0, 0);
    __syncthreads();
  }

  for (int x = tid; x < 640; x += 256) ep[x] = attn[(size_t)brow * TOPK + x];
  for (int x = tid; x < 640; x += 256) { int j = x >> 7, c = x & 127; ep[640 + x]  = VW[j*D + bcol + c]; }
  for (int x = tid; x < 640; x += 256) { int j = x >> 7, c = x & 127; ep[1280 + x] = vb[j*D + bcol + c]; }
  if (tid < 128) ep[1920 + tid] = bg[bcol + tid];
  __syncthreads();

#pragma unroll
  for (int m = 0; m < 4; ++m) {
    int rbase = wr * 64 + m * 16 + fg * 4;
#pragma unroll
    for (int n = 0; n < 4; ++n) {
      int c = wc * 64 + n * 16 + fr;
      float vw0 = ep[640 + 0*128 + c], vw1 = ep[640 + 1*128 + c], vw2 = ep[640 + 2*128 + c],
            vw3 = ep[640 + 3*128 + c], vw4 = ep[640 + 4*128 + c];
      float v0 = ep[1280 + 0*128 + c], v1 = ep[1280 + 1*128 + c], v2 = ep[1280 + 2*128 + c],
            v3 = ep[1280 + 3*128 + c], v4 = ep[1280 + 4*128 + c];
      float bgc = ep[1920 + c];
#pragma unroll
      for (int i = 0; i < 4; ++i) {
        int r = rbase + i;
        float a0 = ep[r*5+0], a1 = ep[r*5+1], a2 = ep[r*5+2], a3 = ep[r*5+3], a4 = ep[r*5+4];
        float gl = acc[m][n][i] + bgc + a0*vw0 + a1*vw1 + a2*vw2 + a3*vw3 + a4*vw4;
        float att = a0*v0 + a1*v1 + a2*v2 + a3*v3 + a4*v4;
        float gate = 1.0f / (1.0f + __expf(-gl));
        size_t gi = (size_t)(brow + r) * D + bcol + c;
        out[gi] = no[gi] + gate * att;
      }
    }
  }
}

extern "C" void kernel_launch(void* const* d_in, const int* in_sizes, int n_in,
                              void* d_out, int out_size, void* d_ws, size_t ws_size,
                              hipStream_t stream) {
  (void)in_sizes; (void)n_in; (void)out_size;
  const float* no    = (const float*)d_in[0];
  const float* ce    = (const float*)d_in[1];
  const float* bank  = (const float*)d_in[2];
  const float* mvals = (const float*)d_in[3];
  const float* Wq    = (const float*)d_in[4];
  const float* bq    = (const float*)d_in[5];
  const float* Wk    = (const float*)d_in[6];
  const float* bk    = (const float*)d_in[7];
  const float* Wv    = (const float*)d_in[8];
  const float* bvp   = (const float*)d_in[9];
  const float* Wg    = (const float*)d_in[10];
  const float* bg    = (const float*)d_in[11];
  float* out = (float*)d_out;

  char* ws = (char*)d_ws;
  float* top_sims = (float*)(ws + 220160);
  int*   top_idx  = (int*)  (ws + 220192);
  float* sbias    = (float*)(ws + 220224);
  float* kb       = (float*)(ws + 221184);
  float* vb       = (float*)(ws + 262144);
  float* VW       = (float*)(ws + 303104);
  float* KQpart   = (float*)(ws + 344064);   // 1.31 MB -> ends 1654784
  float* KQ       = (float*)(ws + 1654784);  // 40 KB -> ends 1695744
  float* attn     = (float*)(ws + 1695744);  // 327 KB -> ends 2023424
  float* bval     = (float*)(ws + 2023424);  // 40 KB
  int*   bidx     = (int*)  (ws + 2064384);  // 40 KB -> ends 2105344
  unsigned short* A_sw = (unsigned short*)(ws + 4194304);
  unsigned short* B_sw = (unsigned short*)(ws + 4194304 + (size_t)B_ROWS * D * 2);

  const size_t ws_need = 4194304 + (size_t)B_ROWS * D * 2 + (size_t)D * D * 2;
  const bool fast = ws_size >= ws_need;

  if (fast) k_sims<true><<<2080, 256, 0, stream>>>(bank, ce, bval, bidx, Wg, B_sw);
  else      k_sims<false><<<2048, 256, 0, stream>>>(bank, ce, bval, bidx, Wg, B_sw);
  k_topk<<<1, 1024, 0, stream>>>(bval, bidx, top_sims, top_idx);
  k_kv<<<512, 256, 0, stream>>>(mvals, top_idx, Wk, bk, Wv, bvp, kb, vb);
  k_prep<<<769, 256, 0, stream>>>(Wq, bq, Wg, kb, vb, KQpart, VW, sbias);
  k_red<<<40, 256, 0, stream>>>(KQpart, KQ);
  if (fast) {
    k_attn<true><<<512, 512, 0, stream>>>(no, KQ, sbias, top_sims, attn, A_sw);
    k_gemm_bf<<<512, 512, 0, stream>>>(A_sw, B_sw, bg, attn, vb, VW, out);
  } else {
    k_attn<false><<<512, 512, 0, stream>>>(no, KQ, sbias, top_sims, attn, A_sw);
    k_gemm_f32<<<dim3(B_ROWS / BM, D / BN), 256, 0, stream>>>(no, Wg, bg, attn, vb, VW, out);
  }
}